// Round 5
// baseline (373.459 us; speedup 1.0000x reference)
//
#include <hip/hip_runtime.h>
#include <hip/hip_bf16.h>
#include <math.h>

typedef short short8 __attribute__((ext_vector_type(8)));
typedef short short4_t __attribute__((ext_vector_type(4)));
typedef float f32x4 __attribute__((ext_vector_type(4)));
typedef unsigned short u16;
typedef unsigned int u32;

#define B_ 2
#define S_ 2048
#define E_ 1024
#define H_ 16
#define D_ 64
#define TOK (B_*S_)

__device__ __forceinline__ float bf2f(u16 u) {
    union { unsigned int u; float f; } v; v.u = ((unsigned int)u) << 16; return v.f;
}
__device__ __forceinline__ u16 f2bf(float f) {
    union { float f; unsigned int u; } v; v.f = f;
    unsigned int r = v.u + 0x7fffu + ((v.u >> 16) & 1u);
    return (u16)(r >> 16);
}
__device__ __forceinline__ u32 fbits(float f) {
    union { float f; u32 u; } v; v.f = f; return v.u;
}
__device__ __forceinline__ void gl_lds16(const u16* g, short* l) {
    __builtin_amdgcn_global_load_lds(
        (const __attribute__((address_space(1))) unsigned int*)(g),
        (__attribute__((address_space(3))) unsigned int*)(l), 16, 0, 0);
}

// ================= fused prepass bodies =================

__device__ __forceinline__ void convf_body(const float* __restrict__ s, u16* __restrict__ d,
                                           int blk, int tid)
{
    size_t i = ((size_t)blk * 256 + tid) * 8;
    f32x4 a = *(const f32x4*)(s + i);
    f32x4 b = *(const f32x4*)(s + i + 4);
    short8 r;
#pragma unroll
    for (int j = 0; j < 4; j++) { r[j] = (short)f2bf(a[j]); r[4 + j] = (short)f2bf(b[j]); }
    *(short8*)(d + i) = r;
}

__device__ __forceinline__ void tconv_body(const float* __restrict__ src, u16* __restrict__ dst,
                                           int K, int N, int bx, int by, u16 (*t)[72], int tid)
{
    int k0 = by * 64, n0 = bx * 64;
    int kr = tid >> 4, nc = (tid & 15) * 4;
#pragma unroll
    for (int i = 0; i < 4; i++) {
        f32x4 v = *(const f32x4*)(src + (size_t)(k0 + kr + i * 16) * N + n0 + nc);
#pragma unroll
        for (int j = 0; j < 4; j++) t[kr + i * 16][nc + j] = f2bf(v[j]);
    }
    __syncthreads();
    int nr = tid >> 2, kg = (tid & 3) * 16;
    short8 r0, r1;
#pragma unroll
    for (int j = 0; j < 8; j++) { r0[j] = (short)t[kg + j][nr]; r1[j] = (short)t[kg + 8 + j][nr]; }
    u16* dp = dst + (size_t)(n0 + nr) * K + k0 + kg;
    *(short8*)(dp) = r0;
    *(short8*)(dp + 8) = r1;
}

__device__ __forceinline__ void tconvqkv_body(const float* __restrict__ wq, const float* __restrict__ wk,
                                              const float* __restrict__ wv, u16* __restrict__ dst,
                                              int z, int yy, u16 (*t)[72], int tid)
{
    int w = z >> 4, hh = z & 15;
    const float* src = (w == 0 ? wq : (w == 1 ? wk : wv)) + (size_t)hh * E_ * D_;
    u16* d = dst + (size_t)w * E_ * E_ + (size_t)hh * D_ * E_;
    int k0 = yy * 64;
    int kr = tid >> 4, nc = (tid & 15) * 4;
#pragma unroll
    for (int i = 0; i < 4; i++) {
        f32x4 v = *(const f32x4*)(src + (size_t)(k0 + kr + i * 16) * D_ + nc);
#pragma unroll
        for (int j = 0; j < 4; j++) t[kr + i * 16][nc + j] = f2bf(v[j]);
    }
    __syncthreads();
    int nr = tid >> 2, kg = (tid & 3) * 16;
    short8 r0, r1;
#pragma unroll
    for (int j = 0; j < 8; j++) { r0[j] = (short)t[kg + j][nr]; r1[j] = (short)t[kg + 8 + j][nr]; }
    u16* dp = d + (size_t)nr * E_ + k0 + kg;
    *(short8*)(dp) = r0;
    *(short8*)(dp + 8) = r1;
}

__device__ __forceinline__ void maskprep_body(const int* __restrict__ mask, float* __restrict__ fb,
                                              int* __restrict__ ok, int b, int tid, unsigned char* fl)
{
    int base = tid * 8;
    unsigned all = 1;
#pragma unroll
    for (int j = 0; j < 8; j++) {
        int m = mask[b * S_ + base + j];
        fb[b * S_ + base + j] = m ? 0.f : -1e9f;
        all &= (m != 0) ? 1u : 0u;
    }
    fl[tid] = (unsigned char)all;
    __syncthreads();
    if (tid < 32) {
        unsigned a = 1;
#pragma unroll
        for (int j = 0; j < 8; j++) a &= fl[tid * 8 + j];
        ok[b * 32 + tid] = (int)a;
    }
}

template<int INF32>
__device__ __forceinline__ void ln_body(const void* __restrict__ xv, const float* __restrict__ g,
                                        const float* __restrict__ be, u16* __restrict__ y,
                                        int blk, int tid)
{
    int lane = tid & 63, wave = tid >> 6;
    int row = blk * 4 + wave;
    int c0 = lane * 16;
    float v[16];
    if (INF32) {
        const float* xr = (const float*)xv + (size_t)row * E_ + c0;
#pragma unroll
        for (int i = 0; i < 4; i++) {
            f32x4 xx = *(const f32x4*)(xr + i * 4);
#pragma unroll
            for (int j = 0; j < 4; j++) v[i * 4 + j] = xx[j];
        }
    } else {
        const u16* xr = (const u16*)xv + (size_t)row * E_ + c0;
        short8 a = *(const short8*)(xr);
        short8 b = *(const short8*)(xr + 8);
#pragma unroll
        for (int j = 0; j < 8; j++) { v[j] = bf2f((u16)a[j]); v[8 + j] = bf2f((u16)b[j]); }
    }
    float s = 0.f, q = 0.f;
#pragma unroll
    for (int i = 0; i < 16; i++) { s += v[i]; q += v[i] * v[i]; }
#pragma unroll
    for (int off = 1; off < 64; off <<= 1) {
        s += __shfl_xor(s, off, 64);
        q += __shfl_xor(q, off, 64);
    }
    float mu = s * (1.0f / E_);
    float var = q * (1.0f / E_) - mu * mu;
    float rstd = rsqrtf(var + 1e-5f);
    u16* yr = y + (size_t)row * E_ + c0;
    short8 o0, o1;
#pragma unroll
    for (int j = 0; j < 8; j++) {
        o0[j] = (short)f2bf((v[j] - mu) * rstd * g[c0 + j] + be[c0 + j]);
        o1[j] = (short)f2bf((v[8 + j] - mu) * rstd * g[c0 + 8 + j] + be[c0 + 8 + j]);
    }
    *(short8*)(yr) = o0;
    *(short8*)(yr + 8) = o1;
}

// One launch for all independent prepasses (was 7 dispatches).
// Segments: [0,1024) ln1 | [1024,3072) convf | [3072,3840) tconvqkv |
// [3840,4096) tconv proj | [4096,5120) tconv w1 | [5120,6144) tconv w2 | [6144,6146) maskprep
__global__ __launch_bounds__(256) void prep_k(
    const float* __restrict__ I, u16* __restrict__ Ibf,
    const float* __restrict__ wq, const float* __restrict__ wk,
    const float* __restrict__ wv, u16* __restrict__ WTqkv,
    const float* __restrict__ w_proj, u16* __restrict__ WTproj,
    const float* __restrict__ w1, u16* __restrict__ WT1,
    const float* __restrict__ w2, u16* __restrict__ WT2,
    const int* __restrict__ mask, float* __restrict__ fbm, int* __restrict__ okm,
    const float* __restrict__ x, const float* __restrict__ g1,
    const float* __restrict__ be1, u16* __restrict__ xn)
{
    __shared__ __align__(16) u16 tsh[64][72];
    int id = blockIdx.x, tid = threadIdx.x;
    if (id < 1024) {
        ln_body<1>(x, g1, be1, xn, id, tid);
    } else if (id < 3072) {
        convf_body(I, Ibf, id - 1024, tid);
    } else if (id < 3840) {
        int vb = id - 3072;
        tconvqkv_body(wq, wk, wv, WTqkv, vb >> 4, vb & 15, tsh, tid);
    } else if (id < 4096) {
        int vb = id - 3840;
        tconv_body(w_proj, WTproj, E_, E_, vb & 15, vb >> 4, tsh, tid);
    } else if (id < 5120) {
        int vb = id - 4096;
        tconv_body(w1, WT1, E_, 4 * E_, vb & 63, vb >> 6, tsh, tid);
    } else if (id < 6144) {
        int vb = id - 5120;
        tconv_body(w2, WT2, 4 * E_, E_, vb & 15, vb >> 4, tsh, tid);
    } else {
        maskprep_body(mask, fbm, okm, id - 6144, tid, (unsigned char*)tsh);
    }
}

// ---------------- V transpose: V [B,S,H*64] -> Vt [B,H,64,S] ----------------
__global__ __launch_bounds__(256) void vtrans_k(const u16* __restrict__ V, u16* __restrict__ Vt)
{
    __shared__ u16 t[64][72];
    int s0 = blockIdx.x * 64, h = blockIdx.y, b = blockIdx.z;
    int tid = threadIdx.x;
    int sr = tid >> 2, dc = (tid & 3) * 16;
    const u16* src = V + (size_t)b * S_ * E_ + (size_t)(s0 + sr) * E_ + h * D_ + dc;
    short8 v0 = *(const short8*)(src);
    short8 v1 = *(const short8*)(src + 8);
#pragma unroll
    for (int j = 0; j < 8; j++) { t[sr][dc + j] = v0[j]; t[sr][dc + 8 + j] = v1[j]; }
    __syncthreads();
    int dr = tid >> 2, sc = (tid & 3) * 16;
    short8 r0, r1;
#pragma unroll
    for (int j = 0; j < 8; j++) { r0[j] = (short)t[sc + j][dr]; r1[j] = (short)t[sc + 8 + j][dr]; }
    u16* dp = Vt + ((size_t)(b * H_ + h) * D_ + dr) * S_ + s0 + sc;
    *(short8*)(dp) = r0;
    *(short8*)(dp + 8) = r1;
}

// ---------------- LayerNorm (standalone, used for ln2) ----------------
template<int INF32>
__global__ __launch_bounds__(256) void ln_kernel(
    const void* __restrict__ xv, const float* __restrict__ g,
    const float* __restrict__ be, u16* __restrict__ y)
{
    ln_body<INF32>(xv, g, be, y, blockIdx.x, threadIdx.x);
}

// ---------------- 256x256 8-phase GEMM (frozen at R4 best) ----------------
template<int QKV, int GELU, int RX>
__global__ __launch_bounds__(512) void gemm8p_k(
    const u16* __restrict__ A, const u16* __restrict__ Axn,
    const u16* __restrict__ WT,
    const float* __restrict__ bq, const float* __restrict__ bk, const float* __restrict__ bv,
    u16* __restrict__ C, int M, int N, int K)
{
    __shared__ __align__(16) short As[2][256 * 64];
    __shared__ __align__(16) short Bs[2][256 * 64];
    int tid = threadIdx.x;
    int wave = tid >> 6, lane = tid & 63, quad = lane >> 4, l16 = lane & 15;
    int wm = wave >> 2, wn = wave & 3;

    int gx = gridDim.x, gy = gridDim.y;
    int lin = blockIdx.y * gx + blockIdx.x;
    int xcd = lin & 7, w = lin >> 3;
    int rw = gx / RX, rh = gy / (8 / RX);
    int bx = (xcd % RX) * rw + (w % rw);
    int by = (xcd / RX) * rh + (w / rw);
    int n0 = bx * 256, m0 = by * 256;

    int which = QKV ? (n0 >> 10) : 0;
    const u16* Ause = (QKV && which) ? Axn : A;
    const float* bias = QKV ? (which == 0 ? bq : (which == 1 ? bk : bv)) : bq;

    f32x4 acc[8][4];
#pragma unroll
    for (int m = 0; m < 8; m++)
#pragma unroll
        for (int n = 0; n < 4; n++)
            acc[m][n] = (f32x4){0.f, 0.f, 0.f, 0.f};

    int srow = lane >> 3, slot = lane & 7;
    const u16* Ag = Ause + (size_t)(m0 + wave * 16 + srow) * K + ((slot ^ srow) << 3);
    const u16* Bg = WT + (size_t)(n0 + wave * 16 + srow) * K + ((slot ^ srow) << 3);
    const size_t r8K = (size_t)8 * K, r128K = (size_t)128 * K, r136K = (size_t)136 * K;
    int wv = wave * 1024;
    int r7 = l16 & 7;
    int soff0 = (quad ^ r7) << 3;
    int soff1 = ((4 + quad) ^ r7) << 3;
    int arow = (wm * 128 + l16) * 64;
    int brow = (wn * 64 + l16) * 64;
    int NT = K >> 6;

#define SB __builtin_amdgcn_sched_barrier(0)
#define GLA2P(P, BUF, H) do { \
    gl_lds16((P) + ((H) ? r128K : (size_t)0), &As[BUF][wv + (H) * 8192]); \
    gl_lds16((P) + ((H) ? r136K : r8K), &As[BUF][wv + (H) * 8192 + 512]); } while (0)
#define GLB2P(P, BUF, H) do { \
    gl_lds16((P) + ((H) ? r128K : (size_t)0), &Bs[BUF][wv + (H) * 8192]); \
    gl_lds16((P) + ((H) ? r136K : r8K), &Bs[BUF][wv + (H) * 8192 + 512]); } while (0)
#define RDA(BUF, Mi, SO) (*(const short8*)(&As[BUF][arow + (Mi) * 1024 + (SO)]))
#define RDB(BUF, Ni, SO) (*(const short8*)(&Bs[BUF][brow + (Ni) * 1024 + (SO)]))
#define MM2(mb, R) do { \
    _Pragma("unroll") \
    for (int n_ = 0; n_ < 4; n_++) { \
        acc[(mb)][n_]     = __builtin_amdgcn_mfma_f32_16x16x32_bf16(R[0], bf[n_][0], acc[(mb)][n_], 0, 0, 0); \
        acc[(mb) + 1][n_] = __builtin_amdgcn_mfma_f32_16x16x32_bf16(R[1], bf[n_][0], acc[(mb) + 1][n_], 0, 0, 0); \
    } \
    _Pragma("unroll") \
    for (int n_ = 0; n_ < 4; n_++) { \
        acc[(mb)][n_]     = __builtin_amdgcn_mfma_f32_16x16x32_bf16(R[2], bf[n_][1], acc[(mb)][n_], 0, 0, 0); \
        acc[(mb) + 1][n_] = __builtin_amdgcn_mfma_f32_16x16x32_bf16(R[3], bf[n_][1], acc[(mb) + 1][n_], 0, 0, 0); \
    } \
} while (0)

#define KTILE(BUF, OBUF, TT, AO, BO) do { \
    SB; __builtin_amdgcn_s_barrier(); \
    short8 bf[4][2], af[4], ag[4]; \
    bf[0][0] = RDB(BUF, 0, soff0); bf[1][0] = RDB(BUF, 1, soff0); \
    bf[2][0] = RDB(BUF, 2, soff0); bf[3][0] = RDB(BUF, 3, soff0); \
    af[0] = RDA(BUF, 0, soff0); af[1] = RDA(BUF, 1, soff0); \
    bf[0][1] = RDB(BUF, 0, soff1); bf[1][1] = RDB(BUF, 1, soff1); \
    bf[2][1] = RDB(BUF, 2, soff1); bf[3][1] = RDB(BUF, 3, soff1); \
    af[2] = RDA(BUF, 0, soff1); af[3] = RDA(BUF, 1, soff1); \
    if ((TT) + 1 < NT) GLA2P((AO), OBUF, 0); \
    __builtin_amdgcn_s_setprio(1); MM2(0, af); __builtin_amdgcn_s_setprio(0); \
    ag[0] = RDA(BUF, 2, soff0); ag[1] = RDA(BUF, 3, soff0); \
    ag[2] = RDA(BUF, 2, soff1); ag[3] = RDA(BUF, 3, soff1); \
    SB; __builtin_amdgcn_s_barrier(); \
    if ((TT) + 1 < NT) GLA2P((AO), OBUF, 1); \
    __builtin_amdgcn_s_setprio(1); MM2(2, ag); __builtin_amdgcn_s_setprio(0); \
    af[0] = RDA(BUF, 4, soff0); af[1] = RDA(BUF, 5, soff0); \
    af[2] = RDA(BUF, 4, soff1); af[3] = RDA(BUF, 5, soff1); \
    SB; __builtin_amdgcn_s_barrier(); \
    if ((TT) + 2 < NT) GLB2P((BO), BUF, 0); \
    __builtin_amdgcn_s_setprio(1); MM2(4, af); __builtin_amdgcn_s_setprio(0); \
    ag[0] = RDA(BUF, 6, soff0); ag[1] = RDA(BUF, 7, soff0); \
    ag[2] = RDA(BUF, 6, soff1); ag[3] = RDA(BUF, 7, soff1); \
    SB; __builtin_amdgcn_s_barrier(); \
    if ((TT) + 2 < NT) GLB2P((BO), BUF, 1); \
    __builtin_amdgcn_s_setprio(1); MM2(6, ag); __builtin_amdgcn_s_setprio(0); \
    if ((TT) + 2 < NT) { asm volatile("s_waitcnt vmcnt(4)" ::: "memory"); } \
    else               { asm volatile("s_waitcnt vmcnt(0)" ::: "memory"); } \
    SB; \
} while (0)

    GLB2P(Bg, 0, 0); GLB2P(Bg, 0, 1);
    GLA2P(Ag, 0, 0); GLA2P(Ag, 0, 1);
    if (NT > 1) {
        GLB2P(Bg + 64, 1, 0); GLB2P(Bg + 64, 1, 1);
        asm volatile("s_waitcnt vmcnt(4)" ::: "memory");
    } else {
        asm volatile("s_waitcnt vmcnt(0)" ::: "memory");
    }

    const u16* A1 = Ag + 64;
    const u16* B2 = Bg + 128;
    for (int t = 0; t < NT; t += 2) {
        KTILE(0, 1, t, A1, B2);
        KTILE(1, 0, t + 1, A1 + 64, B2 + 64);
        A1 += 128; B2 += 128;
    }

    u16* Cw = QKV ? (C + (size_t)which * (size_t)M * 1024) : C;
    int ostride = QKV ? 1024 : N;
#pragma unroll
    for (int m = 0; m < 8; m++) {
#pragma unroll
        for (int n = 0; n < 4; n++) {
            int colg = n0 + wn * 64 + n * 16 + l16;
            int col = QKV ? (colg & 1023) : colg;
            float bb = bias[col];
#pragma unroll
            for (int r = 0; r < 4; r++) {
                int row = m0 + wm * 128 + m * 16 + quad * 4 + r;
                float v = acc[m][n][r] + bb;
                if (QKV && which == 0) v *= 0.03125f;
                if (GELU) v = 0.5f * v * (1.0f + erff(v * 0.70710678118f));
                Cw[(size_t)row * ostride + col] = f2bf(v);
            }
        }
    }
#undef SB
#undef GLA2P
#undef GLB2P
#undef RDA
#undef RDB
#undef MM2
#undef KTILE
}

// ---------------- split-K GEMM BK=64: bf16 partials (+XCD swizzle) ----------------
__global__ __launch_bounds__(256) void gemmsk_k(
    const u16* __restrict__ A, const u16* __restrict__ WT,
    u16* __restrict__ P, int M, int N, int K, int Ks)
{
    __shared__ __align__(16) short a_sh[2][128 * 32];
    __shared__ __align__(16) short b_sh[2][128 * 32];
    int tid = threadIdx.x;
    int wave = tid >> 6, lane = tid & 63, quad = lane >> 4, l16 = lane & 15;
    int wm = wave >> 1, wn = wave & 1;
    int gx = gridDim.x;
    int lin = blockIdx.y * gx + blockIdx.x;
    int xcd = lin & 7, w = lin >> 3;
    int rh = gridDim.y >> 3;
    int bx = w % gx, by = xcd * rh + (w / gx);
    int m0 = by * 128, n0 = bx * 128;
    int koff = blockIdx.z * Ks;

    f32x4 acc[4][4];
#pragma unroll
    for (int mt = 0; mt < 4; mt++)
#pragma unroll
        for (int nt = 0; nt < 4; nt++)
            acc[mt][nt] = (f32x4){0.f, 0.f, 0.f, 0.f};

    int srow = lane >> 2;
    int c = ((lane & 3) ^ ((lane >> 3) & 3)) * 8;
    const u16* Ab = A + (size_t)(m0 + wave * 32 + srow) * K + koff + c;
    const u16* Bb = WT + (size_t)(n0 + wave * 32 + srow) * K + koff + c;
    short* al0 = &a_sh[0][wave * 1024];
    short* al1 = &a_sh[1][wave * 1024];
    short* bl0 = &b_sh[0][wave * 1024];
    short* bl1 = &b_sh[1][wave * 1024];
    int xo = (quad ^ ((l16 >> 1) & 3)) * 8;

    for (int kk = 0; kk < Ks; kk += 64) {
        __syncthreads();
        gl_lds16(Ab + kk, al0);
        gl_lds16(Ab + kk + (size_t)16 * K, al0 + 512);
        gl_lds16(Ab + kk + 32, al1);
        gl_lds16(Ab + kk + (size_t)16 * K + 32, al1 + 512);
        gl_lds16(Bb + kk, bl0);
        gl_lds16(Bb + kk + (size_t)16 * K, bl0 + 512);
        gl_lds16(Bb + kk + 32, bl1);
        gl_lds16(Bb + kk + (size_t)16 * K + 32, bl1 + 512);
        __syncthreads();

#pragma unroll
        for (int h = 0; h < 2; h++) {
            short8 af[4], bf8[4];
#pragma unroll
            for (int mt = 0; mt < 4; mt++)
                af[mt] = *(const short8*)(&a_sh[h][(wm * 64 + mt * 16 + l16) * 32 + xo]);
#pragma unroll
            for (int nt = 0; nt < 4; nt++)
                bf8[nt] = *(const short8*)(&b_sh[h][(wn * 64 + nt * 16 + l16) * 32 + xo]);
#pragma unroll
            for (int mt = 0; mt < 4; mt++)
#pragma unroll
                for (int nt = 0; nt < 4; nt++)
                    acc[mt][nt] = __builtin_amdgcn_mfma_f32_16x16x32_bf16(af[mt], bf8[nt], acc[mt][nt], 0, 0, 0);
        }
    }

    u16* Pz = P + (size_t)blockIdx.z * (size_t)M * N;
#pragma unroll
    for (int mt = 0; mt < 4; mt++) {
#pragma unroll
        for (int nt = 0; nt < 4; nt++) {
            int col = n0 + wn * 64 + nt * 16 + l16;
#pragma unroll
            for (int r = 0; r < 4; r++) {
                int row = m0 + wm * 64 + mt * 16 + quad * 4 + r;
                Pz[(size_t)row * N + col] = f2bf(acc[mt][nt][r]);
            }
        }
    }
}

// ---------------- combine 2 bf16 partials + bias + residual -> f32 out ----------------
__global__ __launch_bounds__(256) void combine2_k(
    const u16* __restrict__ P, const float* __restrict__ bias,
    const u16* __restrict__ res, float* __restrict__ out)
{
    const size_t MN = (size_t)TOK * E_;
    size_t i = ((size_t)blockIdx.x * 256 + threadIdx.x) * 8;
    int col = (int)(i & (E_ - 1));
    float v[8];
    f32x4 b0 = *(const f32x4*)(bias + col);
    f32x4 b1 = *(const f32x4*)(bias + col + 4);
    short8 rr = *(const short8*)(res + i);
#pragma unroll
    for (int j = 0; j < 4; j++) { v[j] = b0[j] + bf2f((u16)rr[j]); v[4 + j] = b1[j] + bf2f((u16)rr[4 + j]); }
#pragma unroll
    for (int z = 0; z < 2; z++) {
        short8 p = *(const short8*)(P + z * MN + i);
#pragma unroll
        for (int j = 0; j < 8; j++) v[j] += bf2f((u16)p[j]);
    }
    f32x4 o0, o1;
#pragma unroll
    for (int j = 0; j < 4; j++) { o0[j] = v[j]; o1[j] = v[4 + j]; }
    *(f32x4*)(out + i) = o0;
    *(f32x4*)(out + i + 4) = o1;
}

// ---------------- 128x64 bf16 GEMM BK=64 for N=1024 shapes ----------------
template<int GELU, int RES, int CF32>
__global__ __launch_bounds__(256) void gemm3_k(
    const u16* __restrict__ A, const u16* __restrict__ WT,
    const float* __restrict__ bias, const u16* __restrict__ res,
    void* __restrict__ Cv, int M, int N, int K)
{
    __shared__ __align__(16) short a_sh[2][128 * 32];
    __shared__ __align__(16) short b_sh[2][64 * 32];
    int tid = threadIdx.x;
    int wave = tid >> 6, lane = tid & 63, quad = lane >> 4, l16 = lane & 15;
    int wm = wave >> 1, wn = wave & 1;
    int m0 = blockIdx.y * 128, n0 = blockIdx.x * 64;

    f32x4 acc[4][2];
#pragma unroll
    for (int mt = 0; mt < 4; mt++)
#pragma unroll
        for (int nt = 0; nt < 2; nt++)
            acc[mt][nt] = (f32x4){0.f, 0.f, 0.f, 0.f};

    int srow = lane >> 2;
    int c = ((lane & 3) ^ ((lane >> 3) & 3)) * 8;
    const u16* Ab = A + (size_t)(m0 + wave * 32 + srow) * K + c;
    const u16* Bb = WT + (size_t)(n0 + wave * 16 + srow) * K + c;
    short* al0 = &a_sh[0][wave * 1024];
    short* al1 = &a_sh[1][wave * 1024];
    short* bl0 = &b_sh[0][wave * 512];
    short* bl1 = &b_sh[1][wave * 512];
    int xo = (quad ^ ((l16 >> 1) & 3)) * 8;

    for (int kk = 0; kk < K; kk += 64) {
        __syncthreads();
        gl_lds16(Ab + kk, al0);
        gl_lds16(Ab + kk + (size_t)16 * K, al0 + 512);
        gl_lds16(Ab + kk + 32, al1);
        gl_lds16(Ab + kk + (size_t)16 * K + 32, al1 + 512);
        gl_lds16(Bb + kk, bl0);
        gl_lds16(Bb + kk + 32, bl1);
        __syncthreads();

#pragma unroll
        for (int h = 0; h < 2; h++) {
            short8 af[4], bf8[2];
#pragma unroll
            for (int mt = 0; mt < 4; mt++)
                af[mt] = *(const short8*)(&a_sh[h][(wm * 64 + mt * 16 + l16) * 32 + xo]);
#pragma unroll
            for (int nt = 0; nt < 2; nt++)
                bf8[nt] = *(const short8*)(&b_sh[h][(wn * 32 + nt * 16 + l16) * 32 + xo]);
#pragma unroll
            for (int mt = 0; mt < 4; mt++)
#pragma unroll
                for (int nt = 0; nt < 2; nt++)
                    acc[mt][nt] = __builtin_amdgcn_mfma_f32_16x16x32_bf16(af[mt], bf8[nt], acc[mt][nt], 0, 0, 0);
        }
    }

#pragma unroll
    for (int mt = 0; mt < 4; mt++) {
#pragma unroll
        for (int nt = 0; nt < 2; nt++) {
            int col = n0 + wn * 32 + nt * 16 + l16;
            float bb = bias[col];
#pragma unroll
            for (int r = 0; r < 4; r++) {
                int row = m0 + wm * 64 + mt * 16 + quad * 4 + r;
                float v = acc[mt][nt][r] + bb;
                if (RES) v += bf2f(res[(size_t)row * N + col]);
                if (GELU) v = 0.5f * v * (1.0f + erff(v * 0.70710678118f));
                if (CF32) ((float*)Cv)[(size_t)row * N + col] = v;
                else ((u16*)Cv)[(size_t)row * N + col] = f2bf(v);
            }
        }
    }
}

// ---------------- Flash attention v5: 4 waves x 32 q-rows (2x intensity per staged tile) ----------------
// Same verified fragment layouts as v4; second q-half is additive. K-frag and V-frag
// ds_reads amortize over both q-halves (32 MFMA per 20 b128 reads per tile per wave).
// One __syncthreads per K/V tile (double-buffered; compiler drains vmcnt before barrier).
__global__ __launch_bounds__(256) void attn_k(
    const u16* __restrict__ Q, const u16* __restrict__ K,
    const u16* __restrict__ Vt, const float* __restrict__ fb,
    const int* __restrict__ ok, u16* __restrict__ O)
{
    __shared__ __align__(16) short k_sh[2][2][64 * 32];  // [buf][d-half][key][32]
    __shared__ __align__(16) short v_sh[2][2][64 * 32];  // [buf][key-half][d][32]
    __shared__ __align__(16) short p_sh[4][32 * 72];     // per-wave P [q 32][key 64+pad]
    int tid = threadIdx.x;
    int wave = tid >> 6, lane = tid & 63, quad = lane >> 4, l16 = lane & 15;
    int qb = blockIdx.x, h = blockIdx.y, b = blockIdx.z;
    int q0 = qb * 128;
    const u16* Qp = Q + (size_t)b * S_ * E_ + (size_t)h * D_;
    const u16* Kp = K + (size_t)b * S_ * E_ + (size_t)h * D_;
    const u16* Vtp = Vt + (size_t)(b * H_ + h) * D_ * S_;

    int qrA = q0 + wave * 32 + l16;
    short8 qfA0 = *(const short8*)(Qp + (size_t)qrA * E_ + quad * 8);
    short8 qfA1 = *(const short8*)(Qp + (size_t)qrA * E_ + 32 + quad * 8);
    short8 qfB0 = *(const short8*)(Qp + (size_t)(qrA + 16) * E_ + quad * 8);
    short8 qfB1 = *(const short8*)(Qp + (size_t)(qrA + 16) * E_ + 32 + quad * 8);

    f32x4 oA[4], oB[4];
#pragma unroll
    for (int dt = 0; dt < 4; dt++) { oA[dt] = (f32x4){0.f,0.f,0.f,0.f}; oB[dt] = (f32x4){0.f,0.f,0.f,0.f}; }
    float rsA = 0.f, rsB = 0.f;

    // staging: wave w stages rows [w*16, w*16+16) of K (keys) and Vt (d) for both 32-col halves
    int srow = lane >> 2;
    int c = ((lane & 3) ^ ((lane >> 3) & 3)) * 8;
    const u16* Kg = Kp + (size_t)(wave * 16 + srow) * E_ + c;
    const u16* Vg = Vtp + (size_t)(wave * 16 + srow) * S_ + c;

    gl_lds16(Kg,      &k_sh[0][0][wave * 512]);
    gl_lds16(Kg + 32, &k_sh[0][1][wave * 512]);
    gl_lds16(Vg,      &v_sh[0][0][wave * 512]);
    gl_lds16(Vg + 32, &v_sh[0][1][wave * 512]);
    __syncthreads();

    const float* fbb = fb + b * S_;
    const int* okb = ok + b * 32;
    int xo = (quad ^ ((l16 >> 1) & 3)) * 8;

    for (int kt = 0; kt < S_ / 64; kt++) {
        int cur = kt & 1;
        if (kt < 31) {
            const u16* Kn = Kg + (size_t)(kt + 1) * 64 * E_;
            const u16* Vn = Vg + (kt + 1) * 64;
            gl_lds16(Kn,      &k_sh[cur ^ 1][0][wave * 512]);
            gl_lds16(Kn + 32, &k_sh[cur ^ 1][1][wave * 512]);
            gl_lds16(Vn,      &v_sh[cur ^ 1][0][wave * 512]);
            gl_lds16(Vn + 32, &v_sh[cur ^ 1][1][wave * 512]);
        }

        // S^T = K Q^T for both q-halves (K-frags shared)
        f32x4 sA[4], sB[4];
#pragma unroll
        for (int mt = 0; mt < 4; mt++) {
            int ro = (mt * 16 + l16) * 32 + xo;
            short8 kf0 = *(const short8*)(&k_sh[cur][0][ro]);
            short8 kf1 = *(const short8*)(&k_sh[cur][1][ro]);
            sA[mt] = __builtin_amdgcn_mfma_f32_16x16x32_bf16(kf0, qfA0, (f32x4){0.f,0.f,0.f,0.f}, 0, 0, 0);
            sA[mt] = __builtin_amdgcn_mfma_f32_16x16x32_bf16(kf1, qfA1, sA[mt], 0, 0, 0);
            sB[mt] = __builtin_amdgcn_mfma_f32_16x16x32_bf16(kf0, qfB0, (f32x4){0.f,0.f,0.f,0.f}, 0, 0, 0);
            sB[mt] = __builtin_amdgcn_mfma_f32_16x16x32_bf16(kf1, qfB1, sB[mt], 0, 0, 0);
        }

        if (!okb[kt]) {
#pragma unroll
            for (int mt = 0; mt < 4; mt++)
#pragma unroll
                for (int r = 0; r < 4; r++) {
                    float fv = fbb[kt * 64 + mt * 16 + quad * 4 + r];
                    sA[mt][r] += fv;
                    sB[mt][r] += fv;
                }
        }

#pragma unroll
        for (int mt = 0; mt < 4; mt++) {
            float a0 = __expf(sA[mt][0]), a1 = __expf(sA[mt][1]);
            float a2 = __expf(sA[mt][2]), a3 = __expf(sA[mt][3]);
            rsA += (a0 + a1) + (a2 + a3);
            u32 ua0 = __builtin_amdgcn_perm(fbits(a1), fbits(a0), 0x07060302u);
            u32 ua1 = __builtin_amdgcn_perm(fbits(a3), fbits(a2), 0x07060302u);
            uint2 pka; pka.x = ua0; pka.y = ua1;
            *(uint2*)(&p_sh[wave][l16 * 72 + mt * 16 + quad * 4]) = pka;

            float b0 = __expf(sB[mt][0]), b1v = __expf(sB[mt][1]);
            float b2 = __expf(sB[mt][2]), b3 = __expf(sB[mt][3]);
            rsB += (b0 + b1v) + (b2 + b3);
            u32 ub0 = __builtin_amdgcn_perm(fbits(b1v), fbits(b0), 0x07060302u);
            u32 ub1 = __builtin_amdgcn_perm(fbits(b3), fbits(b2), 0x07060302u);
            uint2 pkb; pkb.x = ub0; pkb.y = ub1;
            *(uint2*)(&p_sh[wave][(16 + l16) * 72 + mt * 16 + quad * 4]) = pkb;
        }

        // O^T += V^T P^T for both halves (V-frags shared)
#pragma unroll
        for (int sk = 0; sk < 2; sk++) {
            short8 pfA = *(const short8*)(&p_sh[wave][l16 * 72 + sk * 32 + quad * 8]);
            short8 pfB = *(const short8*)(&p_sh[wave][(16 + l16) * 72 + sk * 32 + quad * 8]);
#pragma unroll
            for (int dt = 0; dt < 4; dt++) {
                short8 vf = *(const short8*)(&v_sh[cur][sk][(dt * 16 + l16) * 32 + xo]);
                oA[dt] = __builtin_amdgcn_mfma_f32_16x16x32_bf16(vf, pfA, oA[dt], 0, 0, 0);
                oB[dt] = __builtin_amdgcn_mfma_f32_16x16x32_bf16(vf, pfB, oB[dt], 0, 0, 0);
            }
        }
        __syncthreads();
    }

    rsA += __shfl_xor(rsA, 16, 64);
    rsA += __shfl_xor(rsA, 32, 64);
    rsB += __shfl_xor(rsB, 16, 64);
    rsB += __shfl_xor(rsB, 32, 64);
    float invA = 1.0f / rsA;
    float invB = 1.0f / rsB;
    u16* OpA = O + (size_t)b * S_ * E_ + (size_t)qrA * E_ + h * D_;
    u16* OpB = OpA + (size_t)16 * E_;
#pragma unroll
    for (int dt = 0; dt < 4; dt++) {
        short4_t pk;
#pragma unroll
        for (int r = 0; r < 4; r++) pk[r] = (short)f2bf(oA[dt][r] * invA);
        *(short4_t*)(OpA + dt * 16 + quad * 4) = pk;
        short4_t pk2;
#pragma unroll
        for (int r = 0; r < 4; r++) pk2[r] = (short)f2bf(oB[dt][r] * invB);
        *(short4_t*)(OpB + dt * 16 + quad * 4) = pk2;
    }
}

extern "C" void kernel_launch(void* const* d_in, const int* in_sizes, int n_in,
                              void* d_out, int out_size, void* d_ws, size_t ws_size,
                              hipStream_t stream)
{
    (void)in_sizes; (void)n_in; (void)out_size; (void)ws_size;
    const float* I      = (const float*)d_in[0];
    const float* x      = (const float*)d_in[1];
    const int*   mask   = (const int*)d_in[2];
    const float* wq     = (const float*)d_in[3];
    const float* bq     = (const float*)d_in[4];
    const float* wk     = (const float*)d_in[5];
    const float* bk     = (const float*)d_in[6];
    const float* wv     = (const float*)d_in[7];
    const float* bv     = (const float*)d_in[8];
    const float* w_proj = (const float*)d_in[9];
    const float* b_proj = (const float*)d_in[10];
    const float* g1     = (const float*)d_in[11];
    const float* be1    = (const float*)d_in[12];
    const float* g2     = (const float*)d_in[13];
    const float* be2    = (const float*)d_in[14];
    const float* w1     = (const float*)d_in[15];
    const float* b1     = (const float*)d_in[16];
    const float* w2     = (const float*)d_in[17];
    const float* b2     = (const float*)d_in[18];
    float* out = (float*)d_out;

    char* ws = (char*)d_ws;
    const size_t SZ = (size_t)TOK * E_;
    u16* xn   = (u16*)(ws);
    u16* qb_  = (u16*)(ws + SZ * 2);
    u16* kb_  = (u16*)(ws + SZ * 4);
    u16* vb_  = (u16*)(ws + SZ * 6);
    u16* Vt   = (u16*)(ws + SZ * 8);
    u16* Ibf  = (u16*)(ws + SZ * 8);
    u16* ctx  = (u16*)(ws + SZ * 6);
    u16* hb   = (u16*)(ws + SZ * 4);
    u16* h2   = (u16*)(ws);
    u16* a1   = (u16*)(ws + SZ * 2);
    u16* WTqkv  = (u16*)(ws + 40u * 1024 * 1024);
    u16* WTproj = (u16*)(ws + 46u * 1024 * 1024);
    u16* WT1    = (u16*)(ws + 48u * 1024 * 1024);
    u16* WT2    = (u16*)(ws + 56u * 1024 * 1024);
    u16* Pp     = (u16*)(ws + 40u * 1024 * 1024);
    float* fbm  = (float*)(ws + 40u * 1024 * 1024);
    int*   okm  = (int*)(ws + 40u * 1024 * 1024 + 16384);

    // Fused prepass: ln1 + convf + all 4 weight transposes + maskprep in ONE launch.
    prep_k<<<dim3(6146), 256, 0, stream>>>(
        I, Ibf, wq, wk, wv, WTqkv, w_proj, WTproj, w1, WT1, w2, WT2,
        mask, fbm, okm, x, g1, be1, xn);

    // QKV: 256^2 8-phase, N=3072; RX=2
    gemm8p_k<1,0,2><<<dim3(12, TOK / 256), 512, 0, stream>>>(
        Ibf, xn, WTqkv, bq, bk, bv, qb_, TOK, 3072, E_);

    vtrans_k<<<dim3(S_ / 64, H_, B_), 256, 0, stream>>>(vb_, Vt);

    attn_k<<<dim3(S_ / 128, H_, B_), 256, 0, stream>>>(qb_, kb_, Vt, fbm, okm, ctx);

    gemm3_k<0,1,0><<<dim3(16, TOK / 128), 256, 0, stream>>>(
        ctx, WTproj, b_proj, xn, hb, TOK, E_, E_);
    ln_kernel<0><<<TOK / 4, 256, 0, stream>>>(hb, g2, be2, h2);
    // FFN1: 256^2 8-phase with fused GELU; RX=2
    gemm8p_k<0,1,2><<<dim3(16, TOK / 256), 512, 0, stream>>>(
        h2, nullptr, WT1, b1, nullptr, nullptr, a1, TOK, 4 * E_, E_);
    gemmsk_k<<<dim3(8, TOK / 128, 2), 256, 0, stream>>>(
        a1, WT2, Pp, TOK, E_, 4 * E_, 2 * E_);
    combine2_k<<<dim3(TOK * E_ / (256 * 8)), 256, 0, stream>>>(Pp, b2, h2, out);
}

// Round 6
// 360.967 us; speedup vs baseline: 1.0346x; 1.0346x over previous
//
#include <hip/hip_runtime.h>
#include <hip/hip_bf16.h>
#include <math.h>

typedef short short8 __attribute__((ext_vector_type(8)));
typedef short short4_t __attribute__((ext_vector_type(4)));
typedef float f32x4 __attribute__((ext_vector_type(4)));
typedef unsigned short u16;
typedef unsigned int u32;

#define B_ 2
#define S_ 2048
#define E_ 1024
#define H_ 16
#define D_ 64
#define TOK (B_*S_)

__device__ __forceinline__ float bf2f(u16 u) {
    union { unsigned int u; float f; } v; v.u = ((unsigned int)u) << 16; return v.f;
}
__device__ __forceinline__ u16 f2bf(float f) {
    union { float f; unsigned int u; } v; v.f = f;
    unsigned int r = v.u + 0x7fffu + ((v.u >> 16) & 1u);
    return (u16)(r >> 16);
}
__device__ __forceinline__ u32 fbits(float f) {
    union { float f; u32 u; } v; v.f = f; return v.u;
}
__device__ __forceinline__ void gl_lds16(const u16* g, short* l) {
    __builtin_amdgcn_global_load_lds(
        (const __attribute__((address_space(1))) unsigned int*)(g),
        (__attribute__((address_space(3))) unsigned int*)(l), 16, 0, 0);
}

// ================= fused prepass bodies =================

__device__ __forceinline__ void convf_body(const float* __restrict__ s, u16* __restrict__ d,
                                           int blk, int tid)
{
    size_t i = ((size_t)blk * 256 + tid) * 8;
    f32x4 a = *(const f32x4*)(s + i);
    f32x4 b = *(const f32x4*)(s + i + 4);
    short8 r;
#pragma unroll
    for (int j = 0; j < 4; j++) { r[j] = (short)f2bf(a[j]); r[4 + j] = (short)f2bf(b[j]); }
    *(short8*)(d + i) = r;
}

__device__ __forceinline__ void tconv_body(const float* __restrict__ src, u16* __restrict__ dst,
                                           int K, int N, int bx, int by, u16 (*t)[72], int tid)
{
    int k0 = by * 64, n0 = bx * 64;
    int kr = tid >> 4, nc = (tid & 15) * 4;
#pragma unroll
    for (int i = 0; i < 4; i++) {
        f32x4 v = *(const f32x4*)(src + (size_t)(k0 + kr + i * 16) * N + n0 + nc);
#pragma unroll
        for (int j = 0; j < 4; j++) t[kr + i * 16][nc + j] = f2bf(v[j]);
    }
    __syncthreads();
    int nr = tid >> 2, kg = (tid & 3) * 16;
    short8 r0, r1;
#pragma unroll
    for (int j = 0; j < 8; j++) { r0[j] = (short)t[kg + j][nr]; r1[j] = (short)t[kg + 8 + j][nr]; }
    u16* dp = dst + (size_t)(n0 + nr) * K + k0 + kg;
    *(short8*)(dp) = r0;
    *(short8*)(dp + 8) = r1;
}

__device__ __forceinline__ void tconvqkv_body(const float* __restrict__ wq, const float* __restrict__ wk,
                                              const float* __restrict__ wv, u16* __restrict__ dst,
                                              int z, int yy, u16 (*t)[72], int tid)
{
    int w = z >> 4, hh = z & 15;
    const float* src = (w == 0 ? wq : (w == 1 ? wk : wv)) + (size_t)hh * E_ * D_;
    u16* d = dst + (size_t)w * E_ * E_ + (size_t)hh * D_ * E_;
    int k0 = yy * 64;
    int kr = tid >> 4, nc = (tid & 15) * 4;
#pragma unroll
    for (int i = 0; i < 4; i++) {
        f32x4 v = *(const f32x4*)(src + (size_t)(k0 + kr + i * 16) * D_ + nc);
#pragma unroll
        for (int j = 0; j < 4; j++) t[kr + i * 16][nc + j] = f2bf(v[j]);
    }
    __syncthreads();
    int nr = tid >> 2, kg = (tid & 3) * 16;
    short8 r0, r1;
#pragma unroll
    for (int j = 0; j < 8; j++) { r0[j] = (short)t[kg + j][nr]; r1[j] = (short)t[kg + 8 + j][nr]; }
    u16* dp = d + (size_t)nr * E_ + k0 + kg;
    *(short8*)(dp) = r0;
    *(short8*)(dp + 8) = r1;
}

__device__ __forceinline__ void maskprep_body(const int* __restrict__ mask, float* __restrict__ fb,
                                              int* __restrict__ ok, int b, int tid, unsigned char* fl)
{
    int base = tid * 8;
    unsigned all = 1;
#pragma unroll
    for (int j = 0; j < 8; j++) {
        int m = mask[b * S_ + base + j];
        fb[b * S_ + base + j] = m ? 0.f : -1e9f;
        all &= (m != 0) ? 1u : 0u;
    }
    fl[tid] = (unsigned char)all;
    __syncthreads();
    if (tid < 32) {
        unsigned a = 1;
#pragma unroll
        for (int j = 0; j < 8; j++) a &= fl[tid * 8 + j];
        ok[b * 32 + tid] = (int)a;
    }
}

template<int INF32>
__device__ __forceinline__ void ln_body(const void* __restrict__ xv, const float* __restrict__ g,
                                        const float* __restrict__ be, u16* __restrict__ y,
                                        int blk, int tid)
{
    int lane = tid & 63, wave = tid >> 6;
    int row = blk * 4 + wave;
    int c0 = lane * 16;
    float v[16];
    if (INF32) {
        const float* xr = (const float*)xv + (size_t)row * E_ + c0;
#pragma unroll
        for (int i = 0; i < 4; i++) {
            f32x4 xx = *(const f32x4*)(xr + i * 4);
#pragma unroll
            for (int j = 0; j < 4; j++) v[i * 4 + j] = xx[j];
        }
    } else {
        const u16* xr = (const u16*)xv + (size_t)row * E_ + c0;
        short8 a = *(const short8*)(xr);
        short8 b = *(const short8*)(xr + 8);
#pragma unroll
        for (int j = 0; j < 8; j++) { v[j] = bf2f((u16)a[j]); v[8 + j] = bf2f((u16)b[j]); }
    }
    float s = 0.f, q = 0.f;
#pragma unroll
    for (int i = 0; i < 16; i++) { s += v[i]; q += v[i] * v[i]; }
#pragma unroll
    for (int off = 1; off < 64; off <<= 1) {
        s += __shfl_xor(s, off, 64);
        q += __shfl_xor(q, off, 64);
    }
    float mu = s * (1.0f / E_);
    float var = q * (1.0f / E_) - mu * mu;
    float rstd = rsqrtf(var + 1e-5f);
    u16* yr = y + (size_t)row * E_ + c0;
    short8 o0, o1;
#pragma unroll
    for (int j = 0; j < 8; j++) {
        o0[j] = (short)f2bf((v[j] - mu) * rstd * g[c0 + j] + be[c0 + j]);
        o1[j] = (short)f2bf((v[8 + j] - mu) * rstd * g[c0 + 8 + j] + be[c0 + 8 + j]);
    }
    *(short8*)(yr) = o0;
    *(short8*)(yr + 8) = o1;
}

// One launch for all independent prepasses (was 7 dispatches).
__global__ __launch_bounds__(256) void prep_k(
    const float* __restrict__ I, u16* __restrict__ Ibf,
    const float* __restrict__ wq, const float* __restrict__ wk,
    const float* __restrict__ wv, u16* __restrict__ WTqkv,
    const float* __restrict__ w_proj, u16* __restrict__ WTproj,
    const float* __restrict__ w1, u16* __restrict__ WT1,
    const float* __restrict__ w2, u16* __restrict__ WT2,
    const int* __restrict__ mask, float* __restrict__ fbm, int* __restrict__ okm,
    const float* __restrict__ x, const float* __restrict__ g1,
    const float* __restrict__ be1, u16* __restrict__ xn)
{
    __shared__ __align__(16) u16 tsh[64][72];
    int id = blockIdx.x, tid = threadIdx.x;
    if (id < 1024) {
        ln_body<1>(x, g1, be1, xn, id, tid);
    } else if (id < 3072) {
        convf_body(I, Ibf, id - 1024, tid);
    } else if (id < 3840) {
        int vb = id - 3072;
        tconvqkv_body(wq, wk, wv, WTqkv, vb >> 4, vb & 15, tsh, tid);
    } else if (id < 4096) {
        int vb = id - 3840;
        tconv_body(w_proj, WTproj, E_, E_, vb & 15, vb >> 4, tsh, tid);
    } else if (id < 5120) {
        int vb = id - 4096;
        tconv_body(w1, WT1, E_, 4 * E_, vb & 63, vb >> 6, tsh, tid);
    } else if (id < 6144) {
        int vb = id - 5120;
        tconv_body(w2, WT2, 4 * E_, E_, vb & 15, vb >> 4, tsh, tid);
    } else {
        maskprep_body(mask, fbm, okm, id - 6144, tid, (unsigned char*)tsh);
    }
}

// ---------------- V transpose: V [B,S,H*64] -> Vt [B,H,64,S] ----------------
__global__ __launch_bounds__(256) void vtrans_k(const u16* __restrict__ V, u16* __restrict__ Vt)
{
    __shared__ u16 t[64][72];
    int s0 = blockIdx.x * 64, h = blockIdx.y, b = blockIdx.z;
    int tid = threadIdx.x;
    int sr = tid >> 2, dc = (tid & 3) * 16;
    const u16* src = V + (size_t)b * S_ * E_ + (size_t)(s0 + sr) * E_ + h * D_ + dc;
    short8 v0 = *(const short8*)(src);
    short8 v1 = *(const short8*)(src + 8);
#pragma unroll
    for (int j = 0; j < 8; j++) { t[sr][dc + j] = v0[j]; t[sr][dc + 8 + j] = v1[j]; }
    __syncthreads();
    int dr = tid >> 2, sc = (tid & 3) * 16;
    short8 r0, r1;
#pragma unroll
    for (int j = 0; j < 8; j++) { r0[j] = (short)t[sc + j][dr]; r1[j] = (short)t[sc + 8 + j][dr]; }
    u16* dp = Vt + ((size_t)(b * H_ + h) * D_ + dr) * S_ + s0 + sc;
    *(short8*)(dp) = r0;
    *(short8*)(dp + 8) = r1;
}

// ---------------- LayerNorm (standalone, used for ln2) ----------------
template<int INF32>
__global__ __launch_bounds__(256) void ln_kernel(
    const void* __restrict__ xv, const float* __restrict__ g,
    const float* __restrict__ be, u16* __restrict__ y)
{
    ln_body<INF32>(xv, g, be, y, blockIdx.x, threadIdx.x);
}

// ---------------- 256x256 8-phase GEMM (frozen at R4 best) ----------------
template<int QKV, int GELU, int RX>
__global__ __launch_bounds__(512) void gemm8p_k(
    const u16* __restrict__ A, const u16* __restrict__ Axn,
    const u16* __restrict__ WT,
    const float* __restrict__ bq, const float* __restrict__ bk, const float* __restrict__ bv,
    u16* __restrict__ C, int M, int N, int K)
{
    __shared__ __align__(16) short As[2][256 * 64];
    __shared__ __align__(16) short Bs[2][256 * 64];
    int tid = threadIdx.x;
    int wave = tid >> 6, lane = tid & 63, quad = lane >> 4, l16 = lane & 15;
    int wm = wave >> 2, wn = wave & 3;

    int gx = gridDim.x, gy = gridDim.y;
    int lin = blockIdx.y * gx + blockIdx.x;
    int xcd = lin & 7, w = lin >> 3;
    int rw = gx / RX, rh = gy / (8 / RX);
    int bx = (xcd % RX) * rw + (w % rw);
    int by = (xcd / RX) * rh + (w / rw);
    int n0 = bx * 256, m0 = by * 256;

    int which = QKV ? (n0 >> 10) : 0;
    const u16* Ause = (QKV && which) ? Axn : A;
    const float* bias = QKV ? (which == 0 ? bq : (which == 1 ? bk : bv)) : bq;

    f32x4 acc[8][4];
#pragma unroll
    for (int m = 0; m < 8; m++)
#pragma unroll
        for (int n = 0; n < 4; n++)
            acc[m][n] = (f32x4){0.f, 0.f, 0.f, 0.f};

    int srow = lane >> 3, slot = lane & 7;
    const u16* Ag = Ause + (size_t)(m0 + wave * 16 + srow) * K + ((slot ^ srow) << 3);
    const u16* Bg = WT + (size_t)(n0 + wave * 16 + srow) * K + ((slot ^ srow) << 3);
    const size_t r8K = (size_t)8 * K, r128K = (size_t)128 * K, r136K = (size_t)136 * K;
    int wv = wave * 1024;
    int r7 = l16 & 7;
    int soff0 = (quad ^ r7) << 3;
    int soff1 = ((4 + quad) ^ r7) << 3;
    int arow = (wm * 128 + l16) * 64;
    int brow = (wn * 64 + l16) * 64;
    int NT = K >> 6;

#define SB __builtin_amdgcn_sched_barrier(0)
#define GLA2P(P, BUF, H) do { \
    gl_lds16((P) + ((H) ? r128K : (size_t)0), &As[BUF][wv + (H) * 8192]); \
    gl_lds16((P) + ((H) ? r136K : r8K), &As[BUF][wv + (H) * 8192 + 512]); } while (0)
#define GLB2P(P, BUF, H) do { \
    gl_lds16((P) + ((H) ? r128K : (size_t)0), &Bs[BUF][wv + (H) * 8192]); \
    gl_lds16((P) + ((H) ? r136K : r8K), &Bs[BUF][wv + (H) * 8192 + 512]); } while (0)
#define RDA(BUF, Mi, SO) (*(const short8*)(&As[BUF][arow + (Mi) * 1024 + (SO)]))
#define RDB(BUF, Ni, SO) (*(const short8*)(&Bs[BUF][brow + (Ni) * 1024 + (SO)]))
#define MM2(mb, R) do { \
    _Pragma("unroll") \
    for (int n_ = 0; n_ < 4; n_++) { \
        acc[(mb)][n_]     = __builtin_amdgcn_mfma_f32_16x16x32_bf16(R[0], bf[n_][0], acc[(mb)][n_], 0, 0, 0); \
        acc[(mb) + 1][n_] = __builtin_amdgcn_mfma_f32_16x16x32_bf16(R[1], bf[n_][0], acc[(mb) + 1][n_], 0, 0, 0); \
    } \
    _Pragma("unroll") \
    for (int n_ = 0; n_ < 4; n_++) { \
        acc[(mb)][n_]     = __builtin_amdgcn_mfma_f32_16x16x32_bf16(R[2], bf[n_][1], acc[(mb)][n_], 0, 0, 0); \
        acc[(mb) + 1][n_] = __builtin_amdgcn_mfma_f32_16x16x32_bf16(R[3], bf[n_][1], acc[(mb) + 1][n_], 0, 0, 0); \
    } \
} while (0)

#define KTILE(BUF, OBUF, TT, AO, BO) do { \
    SB; __builtin_amdgcn_s_barrier(); \
    short8 bf[4][2], af[4], ag[4]; \
    bf[0][0] = RDB(BUF, 0, soff0); bf[1][0] = RDB(BUF, 1, soff0); \
    bf[2][0] = RDB(BUF, 2, soff0); bf[3][0] = RDB(BUF, 3, soff0); \
    af[0] = RDA(BUF, 0, soff0); af[1] = RDA(BUF, 1, soff0); \
    bf[0][1] = RDB(BUF, 0, soff1); bf[1][1] = RDB(BUF, 1, soff1); \
    bf[2][1] = RDB(BUF, 2, soff1); bf[3][1] = RDB(BUF, 3, soff1); \
    af[2] = RDA(BUF, 0, soff1); af[3] = RDA(BUF, 1, soff1); \
    if ((TT) + 1 < NT) GLA2P((AO), OBUF, 0); \
    __builtin_amdgcn_s_setprio(1); MM2(0, af); __builtin_amdgcn_s_setprio(0); \
    ag[0] = RDA(BUF, 2, soff0); ag[1] = RDA(BUF, 3, soff0); \
    ag[2] = RDA(BUF, 2, soff1); ag[3] = RDA(BUF, 3, soff1); \
    SB; __builtin_amdgcn_s_barrier(); \
    if ((TT) + 1 < NT) GLA2P((AO), OBUF, 1); \
    __builtin_amdgcn_s_setprio(1); MM2(2, ag); __builtin_amdgcn_s_setprio(0); \
    af[0] = RDA(BUF, 4, soff0); af[1] = RDA(BUF, 5, soff0); \
    af[2] = RDA(BUF, 4, soff1); af[3] = RDA(BUF, 5, soff1); \
    SB; __builtin_amdgcn_s_barrier(); \
    if ((TT) + 2 < NT) GLB2P((BO), BUF, 0); \
    __builtin_amdgcn_s_setprio(1); MM2(4, af); __builtin_amdgcn_s_setprio(0); \
    ag[0] = RDA(BUF, 6, soff0); ag[1] = RDA(BUF, 7, soff0); \
    ag[2] = RDA(BUF, 6, soff1); ag[3] = RDA(BUF, 7, soff1); \
    SB; __builtin_amdgcn_s_barrier(); \
    if ((TT) + 2 < NT) GLB2P((BO), BUF, 1); \
    __builtin_amdgcn_s_setprio(1); MM2(6, ag); __builtin_amdgcn_s_setprio(0); \
    if ((TT) + 2 < NT) { asm volatile("s_waitcnt vmcnt(4)" ::: "memory"); } \
    else               { asm volatile("s_waitcnt vmcnt(0)" ::: "memory"); } \
    SB; \
} while (0)

    GLB2P(Bg, 0, 0); GLB2P(Bg, 0, 1);
    GLA2P(Ag, 0, 0); GLA2P(Ag, 0, 1);
    if (NT > 1) {
        GLB2P(Bg + 64, 1, 0); GLB2P(Bg + 64, 1, 1);
        asm volatile("s_waitcnt vmcnt(4)" ::: "memory");
    } else {
        asm volatile("s_waitcnt vmcnt(0)" ::: "memory");
    }

    const u16* A1 = Ag + 64;
    const u16* B2 = Bg + 128;
    for (int t = 0; t < NT; t += 2) {
        KTILE(0, 1, t, A1, B2);
        KTILE(1, 0, t + 1, A1 + 64, B2 + 64);
        A1 += 128; B2 += 128;
    }

    u16* Cw = QKV ? (C + (size_t)which * (size_t)M * 1024) : C;
    int ostride = QKV ? 1024 : N;
#pragma unroll
    for (int m = 0; m < 8; m++) {
#pragma unroll
        for (int n = 0; n < 4; n++) {
            int colg = n0 + wn * 64 + n * 16 + l16;
            int col = QKV ? (colg & 1023) : colg;
            float bb = bias[col];
#pragma unroll
            for (int r = 0; r < 4; r++) {
                int row = m0 + wm * 128 + m * 16 + quad * 4 + r;
                float v = acc[m][n][r] + bb;
                if (QKV && which == 0) v *= 0.03125f;
                if (GELU) v = 0.5f * v * (1.0f + erff(v * 0.70710678118f));
                Cw[(size_t)row * ostride + col] = f2bf(v);
            }
        }
    }
#undef SB
#undef GLA2P
#undef GLB2P
#undef RDA
#undef RDB
#undef MM2
#undef KTILE
}

// ---------------- split-K GEMM BK=64: bf16 partials (+XCD swizzle) ----------------
__global__ __launch_bounds__(256) void gemmsk_k(
    const u16* __restrict__ A, const u16* __restrict__ WT,
    u16* __restrict__ P, int M, int N, int K, int Ks)
{
    __shared__ __align__(16) short a_sh[2][128 * 32];
    __shared__ __align__(16) short b_sh[2][128 * 32];
    int tid = threadIdx.x;
    int wave = tid >> 6, lane = tid & 63, quad = lane >> 4, l16 = lane & 15;
    int wm = wave >> 1, wn = wave & 1;
    int gx = gridDim.x;
    int lin = blockIdx.y * gx + blockIdx.x;
    int xcd = lin & 7, w = lin >> 3;
    int rh = gridDim.y >> 3;
    int bx = w % gx, by = xcd * rh + (w / gx);
    int m0 = by * 128, n0 = bx * 128;
    int koff = blockIdx.z * Ks;

    f32x4 acc[4][4];
#pragma unroll
    for (int mt = 0; mt < 4; mt++)
#pragma unroll
        for (int nt = 0; nt < 4; nt++)
            acc[mt][nt] = (f32x4){0.f, 0.f, 0.f, 0.f};

    int srow = lane >> 2;
    int c = ((lane & 3) ^ ((lane >> 3) & 3)) * 8;
    const u16* Ab = A + (size_t)(m0 + wave * 32 + srow) * K + koff + c;
    const u16* Bb = WT + (size_t)(n0 + wave * 32 + srow) * K + koff + c;
    short* al0 = &a_sh[0][wave * 1024];
    short* al1 = &a_sh[1][wave * 1024];
    short* bl0 = &b_sh[0][wave * 1024];
    short* bl1 = &b_sh[1][wave * 1024];
    int xo = (quad ^ ((l16 >> 1) & 3)) * 8;

    for (int kk = 0; kk < Ks; kk += 64) {
        __syncthreads();
        gl_lds16(Ab + kk, al0);
        gl_lds16(Ab + kk + (size_t)16 * K, al0 + 512);
        gl_lds16(Ab + kk + 32, al1);
        gl_lds16(Ab + kk + (size_t)16 * K + 32, al1 + 512);
        gl_lds16(Bb + kk, bl0);
        gl_lds16(Bb + kk + (size_t)16 * K, bl0 + 512);
        gl_lds16(Bb + kk + 32, bl1);
        gl_lds16(Bb + kk + (size_t)16 * K + 32, bl1 + 512);
        __syncthreads();

#pragma unroll
        for (int h = 0; h < 2; h++) {
            short8 af[4], bf8[4];
#pragma unroll
            for (int mt = 0; mt < 4; mt++)
                af[mt] = *(const short8*)(&a_sh[h][(wm * 64 + mt * 16 + l16) * 32 + xo]);
#pragma unroll
            for (int nt = 0; nt < 4; nt++)
                bf8[nt] = *(const short8*)(&b_sh[h][(wn * 64 + nt * 16 + l16) * 32 + xo]);
#pragma unroll
            for (int mt = 0; mt < 4; mt++)
#pragma unroll
                for (int nt = 0; nt < 4; nt++)
                    acc[mt][nt] = __builtin_amdgcn_mfma_f32_16x16x32_bf16(af[mt], bf8[nt], acc[mt][nt], 0, 0, 0);
        }
    }

    u16* Pz = P + (size_t)blockIdx.z * (size_t)M * N;
#pragma unroll
    for (int mt = 0; mt < 4; mt++) {
#pragma unroll
        for (int nt = 0; nt < 4; nt++) {
            int col = n0 + wn * 64 + nt * 16 + l16;
#pragma unroll
            for (int r = 0; r < 4; r++) {
                int row = m0 + wm * 64 + mt * 16 + quad * 4 + r;
                Pz[(size_t)row * N + col] = f2bf(acc[mt][nt][r]);
            }
        }
    }
}

// ---------------- combine 2 bf16 partials + bias + residual -> f32 out ----------------
__global__ __launch_bounds__(256) void combine2_k(
    const u16* __restrict__ P, const float* __restrict__ bias,
    const u16* __restrict__ res, float* __restrict__ out)
{
    const size_t MN = (size_t)TOK * E_;
    size_t i = ((size_t)blockIdx.x * 256 + threadIdx.x) * 8;
    int col = (int)(i & (E_ - 1));
    float v[8];
    f32x4 b0 = *(const f32x4*)(bias + col);
    f32x4 b1 = *(const f32x4*)(bias + col + 4);
    short8 rr = *(const short8*)(res + i);
#pragma unroll
    for (int j = 0; j < 4; j++) { v[j] = b0[j] + bf2f((u16)rr[j]); v[4 + j] = b1[j] + bf2f((u16)rr[4 + j]); }
#pragma unroll
    for (int z = 0; z < 2; z++) {
        short8 p = *(const short8*)(P + z * MN + i);
#pragma unroll
        for (int j = 0; j < 8; j++) v[j] += bf2f((u16)p[j]);
    }
    f32x4 o0, o1;
#pragma unroll
    for (int j = 0; j < 4; j++) { o0[j] = v[j]; o1[j] = v[4 + j]; }
    *(f32x4*)(out + i) = o0;
    *(f32x4*)(out + i + 4) = o1;
}

// ---------------- 128x64 bf16 GEMM BK=64 for N=1024 shapes ----------------
template<int GELU, int RES, int CF32>
__global__ __launch_bounds__(256) void gemm3_k(
    const u16* __restrict__ A, const u16* __restrict__ WT,
    const float* __restrict__ bias, const u16* __restrict__ res,
    void* __restrict__ Cv, int M, int N, int K)
{
    __shared__ __align__(16) short a_sh[2][128 * 32];
    __shared__ __align__(16) short b_sh[2][64 * 32];
    int tid = threadIdx.x;
    int wave = tid >> 6, lane = tid & 63, quad = lane >> 4, l16 = lane & 15;
    int wm = wave >> 1, wn = wave & 1;
    int m0 = blockIdx.y * 128, n0 = blockIdx.x * 64;

    f32x4 acc[4][2];
#pragma unroll
    for (int mt = 0; mt < 4; mt++)
#pragma unroll
        for (int nt = 0; nt < 2; nt++)
            acc[mt][nt] = (f32x4){0.f, 0.f, 0.f, 0.f};

    int srow = lane >> 2;
    int c = ((lane & 3) ^ ((lane >> 3) & 3)) * 8;
    const u16* Ab = A + (size_t)(m0 + wave * 32 + srow) * K + c;
    const u16* Bb = WT + (size_t)(n0 + wave * 16 + srow) * K + c;
    short* al0 = &a_sh[0][wave * 1024];
    short* al1 = &a_sh[1][wave * 1024];
    short* bl0 = &b_sh[0][wave * 512];
    short* bl1 = &b_sh[1][wave * 512];
    int xo = (quad ^ ((l16 >> 1) & 3)) * 8;

    for (int kk = 0; kk < K; kk += 64) {
        __syncthreads();
        gl_lds16(Ab + kk, al0);
        gl_lds16(Ab + kk + (size_t)16 * K, al0 + 512);
        gl_lds16(Ab + kk + 32, al1);
        gl_lds16(Ab + kk + (size_t)16 * K + 32, al1 + 512);
        gl_lds16(Bb + kk, bl0);
        gl_lds16(Bb + kk + 32, bl1);
        __syncthreads();

#pragma unroll
        for (int h = 0; h < 2; h++) {
            short8 af[4], bf8[2];
#pragma unroll
            for (int mt = 0; mt < 4; mt++)
                af[mt] = *(const short8*)(&a_sh[h][(wm * 64 + mt * 16 + l16) * 32 + xo]);
#pragma unroll
            for (int nt = 0; nt < 2; nt++)
                bf8[nt] = *(const short8*)(&b_sh[h][(wn * 32 + nt * 16 + l16) * 32 + xo]);
#pragma unroll
            for (int mt = 0; mt < 4; mt++)
#pragma unroll
                for (int nt = 0; nt < 2; nt++)
                    acc[mt][nt] = __builtin_amdgcn_mfma_f32_16x16x32_bf16(af[mt], bf8[nt], acc[mt][nt], 0, 0, 0);
        }
    }

#pragma unroll
    for (int mt = 0; mt < 4; mt++) {
#pragma unroll
        for (int nt = 0; nt < 2; nt++) {
            int col = n0 + wn * 32 + nt * 16 + l16;
            float bb = bias[col];
#pragma unroll
            for (int r = 0; r < 4; r++) {
                int row = m0 + wm * 64 + mt * 16 + quad * 4 + r;
                float v = acc[mt][nt][r] + bb;
                if (RES) v += bf2f(res[(size_t)row * N + col]);
                if (GELU) v = 0.5f * v * (1.0f + erff(v * 0.70710678118f));
                if (CF32) ((float*)Cv)[(size_t)row * N + col] = v;
                else ((u16*)Cv)[(size_t)row * N + col] = f2bf(v);
            }
        }
    }
}

// ---------------- Flash attention v4 (reverted): 8 waves x 16 q-rows + XCD head-grouping ----------------
// v5 (4 waves x 32 q) regressed: halved waves/CU lost softmax/staging overlap (rule #23).
// Grid remap: bijective lin->(qb,h,b) so each XCD owns 4 (h,b) pairs -> K/V set 2MB fits L2.
__global__ __launch_bounds__(512) void attn_k(
    const u16* __restrict__ Q, const u16* __restrict__ K,
    const u16* __restrict__ Vt, const float* __restrict__ fb,
    const int* __restrict__ ok, u16* __restrict__ O)
{
    __shared__ __align__(16) short k_sh[2][2][64 * 32];  // [buf][d-half][key][32]
    __shared__ __align__(16) short v_sh[2][2][64 * 32];  // [buf][key-half][d][32]
    __shared__ __align__(16) short p_sh[8][16 * 72];     // per-wave P^T [q][key]
    int tid = threadIdx.x;
    int wave = tid >> 6, lane = tid & 63, quad = lane >> 4, l16 = lane & 15;
    // XCD head-grouping remap (bijective on 512 blocks):
    int lin = blockIdx.x + 16 * (blockIdx.y + 16 * blockIdx.z);
    int xcd = lin & 7, w = lin >> 3;
    int combo = xcd * 4 + (w >> 4);
    int qb = w & 15, h = combo & 15, b = combo >> 4;
    int q0 = qb * 128;
    const u16* Qp = Q + (size_t)b * S_ * E_ + (size_t)h * D_;
    const u16* Kp = K + (size_t)b * S_ * E_ + (size_t)h * D_;
    const u16* Vtp = Vt + (size_t)(b * H_ + h) * D_ * S_;

    int qrow = q0 + wave * 16 + l16;
    short8 qf0 = *(const short8*)(Qp + (size_t)qrow * E_ + quad * 8);
    short8 qf1 = *(const short8*)(Qp + (size_t)qrow * E_ + 32 + quad * 8);

    f32x4 o[4];
#pragma unroll
    for (int dt = 0; dt < 4; dt++) o[dt] = (f32x4){0.f, 0.f, 0.f, 0.f};
    float rs_tot = 0.f;

    int sub = wave & 1, rblk = wave >> 1;
    int srow = lane >> 2;
    int c = ((lane & 3) ^ ((lane >> 3) & 3)) * 8;
    const u16* Kg = Kp + (size_t)(rblk * 16 + srow) * E_ + sub * 32 + c;
    const u16* Vg = Vtp + (size_t)(rblk * 16 + srow) * S_ + sub * 32 + c;
    short* kl0 = &k_sh[0][sub][rblk * 512];
    short* kl1 = &k_sh[1][sub][rblk * 512];
    short* vl0 = &v_sh[0][sub][rblk * 512];
    short* vl1 = &v_sh[1][sub][rblk * 512];

    gl_lds16(Kg, kl0);
    gl_lds16(Vg, vl0);
    __syncthreads();

    const float* fbb = fb + b * S_;
    const int* okb = ok + b * 32;
    int xo = (quad ^ ((l16 >> 1) & 3)) * 8;

    for (int kt = 0; kt < S_ / 64; kt++) {
        int cur = kt & 1;
        if (kt < 31) {
            gl_lds16(Kg + (size_t)(kt + 1) * 64 * E_, cur ? kl0 : kl1);
            gl_lds16(Vg + (kt + 1) * 64, cur ? vl0 : vl1);
        }

        f32x4 s[4];
#pragma unroll
        for (int mt = 0; mt < 4; mt++) {
            int ro = (mt * 16 + l16) * 32 + xo;
            short8 kf0 = *(const short8*)(&k_sh[cur][0][ro]);
            short8 kf1 = *(const short8*)(&k_sh[cur][1][ro]);
            s[mt] = __builtin_amdgcn_mfma_f32_16x16x32_bf16(kf0, qf0, (f32x4){0.f,0.f,0.f,0.f}, 0, 0, 0);
            s[mt] = __builtin_amdgcn_mfma_f32_16x16x32_bf16(kf1, qf1, s[mt], 0, 0, 0);
        }

        if (!okb[kt]) {
#pragma unroll
            for (int mt = 0; mt < 4; mt++)
#pragma unroll
                for (int r = 0; r < 4; r++)
                    s[mt][r] += fbb[kt * 64 + mt * 16 + quad * 4 + r];
        }

#pragma unroll
        for (int mt = 0; mt < 4; mt++) {
            float p0 = __expf(s[mt][0]);
            float p1 = __expf(s[mt][1]);
            float p2 = __expf(s[mt][2]);
            float p3 = __expf(s[mt][3]);
            rs_tot += (p0 + p1) + (p2 + p3);
            u32 u0 = __builtin_amdgcn_perm(fbits(p1), fbits(p0), 0x07060302u);
            u32 u1 = __builtin_amdgcn_perm(fbits(p3), fbits(p2), 0x07060302u);
            uint2 pk; pk.x = u0; pk.y = u1;
            *(uint2*)(&p_sh[wave][l16 * 72 + mt * 16 + quad * 4]) = pk;
        }

#pragma unroll
        for (int sk = 0; sk < 2; sk++) {
            short8 pf = *(const short8*)(&p_sh[wave][l16 * 72 + sk * 32 + quad * 8]);
#pragma unroll
            for (int dt = 0; dt < 4; dt++) {
                short8 vf = *(const short8*)(&v_sh[cur][sk][(dt * 16 + l16) * 32 + xo]);
                o[dt] = __builtin_amdgcn_mfma_f32_16x16x32_bf16(vf, pf, o[dt], 0, 0, 0);
            }
        }
        __syncthreads();
    }

    rs_tot += __shfl_xor(rs_tot, 16, 64);
    rs_tot += __shfl_xor(rs_tot, 32, 64);
    float inv = 1.0f / rs_tot;
    u16* Op = O + (size_t)b * S_ * E_ + (size_t)(q0 + wave * 16 + l16) * E_ + h * D_;
#pragma unroll
    for (int dt = 0; dt < 4; dt++) {
        short4_t pk;
#pragma unroll
        for (int r = 0; r < 4; r++) pk[r] = (short)f2bf(o[dt][r] * inv);
        *(short4_t*)(Op + dt * 16 + quad * 4) = pk;
    }
}

extern "C" void kernel_launch(void* const* d_in, const int* in_sizes, int n_in,
                              void* d_out, int out_size, void* d_ws, size_t ws_size,
                              hipStream_t stream)
{
    (void)in_sizes; (void)n_in; (void)out_size; (void)ws_size;
    const float* I      = (const float*)d_in[0];
    const float* x      = (const float*)d_in[1];
    const int*   mask   = (const int*)d_in[2];
    const float* wq     = (const float*)d_in[3];
    const float* bq     = (const float*)d_in[4];
    const float* wk     = (const float*)d_in[5];
    const float* bk     = (const float*)d_in[6];
    const float* wv     = (const float*)d_in[7];
    const float* bv     = (const float*)d_in[8];
    const float* w_proj = (const float*)d_in[9];
    const float* b_proj = (const float*)d_in[10];
    const float* g1     = (const float*)d_in[11];
    const float* be1    = (const float*)d_in[12];
    const float* g2     = (const float*)d_in[13];
    const float* be2    = (const float*)d_in[14];
    const float* w1     = (const float*)d_in[15];
    const float* b1     = (const float*)d_in[16];
    const float* w2     = (const float*)d_in[17];
    const float* b2     = (const float*)d_in[18];
    float* out = (float*)d_out;

    char* ws = (char*)d_ws;
    const size_t SZ = (size_t)TOK * E_;
    u16* xn   = (u16*)(ws);
    u16* qb_  = (u16*)(ws + SZ * 2);
    u16* kb_  = (u16*)(ws + SZ * 4);
    u16* vb_  = (u16*)(ws + SZ * 6);
    u16* Vt   = (u16*)(ws + SZ * 8);
    u16* Ibf  = (u16*)(ws + SZ * 8);
    u16* ctx  = (u16*)(ws + SZ * 6);
    u16* hb   = (u16*)(ws + SZ * 4);
    u16* h2   = (u16*)(ws);
    u16* a1   = (u16*)(ws + SZ * 2);
    u16* WTqkv  = (u16*)(ws + 40u * 1024 * 1024);
    u16* WTproj = (u16*)(ws + 46u * 1024 * 1024);
    u16* WT1    = (u16*)(ws + 48u * 1024 * 1024);
    u16* WT2    = (u16*)(ws + 56u * 1024 * 1024);
    u16* Pp     = (u16*)(ws + 40u * 1024 * 1024);
    float* fbm  = (float*)(ws + 40u * 1024 * 1024);
    int*   okm  = (int*)(ws + 40u * 1024 * 1024 + 16384);

    // Fused prepass: ln1 + convf + all 4 weight transposes + maskprep in ONE launch.
    prep_k<<<dim3(6146), 256, 0, stream>>>(
        I, Ibf, wq, wk, wv, WTqkv, w_proj, WTproj, w1, WT1, w2, WT2,
        mask, fbm, okm, x, g1, be1, xn);

    // QKV: 256^2 8-phase, N=3072; RX=2
    gemm8p_k<1,0,2><<<dim3(12, TOK / 256), 512, 0, stream>>>(
        Ibf, xn, WTqkv, bq, bk, bv, qb_, TOK, 3072, E_);

    vtrans_k<<<dim3(S_ / 64, H_, B_), 256, 0, stream>>>(vb_, Vt);

    attn_k<<<dim3(S_ / 128, H_, B_), 512, 0, stream>>>(qb_, kb_, Vt, fbm, okm, ctx);

    gemm3_k<0,1,0><<<dim3(16, TOK / 128), 256, 0, stream>>>(
        ctx, WTproj, b_proj, xn, hb, TOK, E_, E_);
    ln_kernel<0><<<TOK / 4, 256, 0, stream>>>(hb, g2, be2, h2);
    // FFN1: 256^2 8-phase with fused GELU; RX=2
    gemm8p_k<0,1,2><<<dim3(16, TOK / 256), 512, 0, stream>>>(
        h2, nullptr, WT1, b1, nullptr, nullptr, a1, TOK, 4 * E_, E_);
    gemmsk_k<<<dim3(8, TOK / 128, 2), 256, 0, stream>>>(
        a1, WT2, Pp, TOK, E_, 4 * E_, 2 * E_);
    combine2_k<<<dim3(TOK * E_ / (256 * 8)), 256, 0, stream>>>(Pp, b2, h2, out);
}

// Round 7
// 357.196 us; speedup vs baseline: 1.0455x; 1.0106x over previous
//
#include <hip/hip_runtime.h>
#include <hip/hip_bf16.h>
#include <math.h>

typedef short short8 __attribute__((ext_vector_type(8)));
typedef short short4_t __attribute__((ext_vector_type(4)));
typedef float f32x4 __attribute__((ext_vector_type(4)));
typedef unsigned short u16;
typedef unsigned int u32;

#define B_ 2
#define S_ 2048
#define E_ 1024
#define H_ 16
#define D_ 64
#define TOK (B_*S_)

__device__ __forceinline__ float bf2f(u16 u) {
    union { unsigned int u; float f; } v; v.u = ((unsigned int)u) << 16; return v.f;
}
__device__ __forceinline__ u16 f2bf(float f) {
    union { float f; unsigned int u; } v; v.f = f;
    unsigned int r = v.u + 0x7fffu + ((v.u >> 16) & 1u);
    return (u16)(r >> 16);
}
__device__ __forceinline__ u32 fbits(float f) {
    union { float f; u32 u; } v; v.f = f; return v.u;
}
__device__ __forceinline__ void gl_lds16(const u16* g, short* l) {
    __builtin_amdgcn_global_load_lds(
        (const __attribute__((address_space(1))) unsigned int*)(g),
        (__attribute__((address_space(3))) unsigned int*)(l), 16, 0, 0);
}

// ================= fused prepass bodies =================

__device__ __forceinline__ void convf_body(const float* __restrict__ s, u16* __restrict__ d,
                                           int blk, int tid)
{
    size_t i = ((size_t)blk * 256 + tid) * 8;
    f32x4 a = *(const f32x4*)(s + i);
    f32x4 b = *(const f32x4*)(s + i + 4);
    short8 r;
#pragma unroll
    for (int j = 0; j < 4; j++) { r[j] = (short)f2bf(a[j]); r[4 + j] = (short)f2bf(b[j]); }
    *(short8*)(d + i) = r;
}

__device__ __forceinline__ void tconv_body(const float* __restrict__ src, u16* __restrict__ dst,
                                           int K, int N, int bx, int by, u16 (*t)[72], int tid)
{
    int k0 = by * 64, n0 = bx * 64;
    int kr = tid >> 4, nc = (tid & 15) * 4;
#pragma unroll
    for (int i = 0; i < 4; i++) {
        f32x4 v = *(const f32x4*)(src + (size_t)(k0 + kr + i * 16) * N + n0 + nc);
#pragma unroll
        for (int j = 0; j < 4; j++) t[kr + i * 16][nc + j] = f2bf(v[j]);
    }
    __syncthreads();
    int nr = tid >> 2, kg = (tid & 3) * 16;
    short8 r0, r1;
#pragma unroll
    for (int j = 0; j < 8; j++) { r0[j] = (short)t[kg + j][nr]; r1[j] = (short)t[kg + 8 + j][nr]; }
    u16* dp = dst + (size_t)(n0 + nr) * K + k0 + kg;
    *(short8*)(dp) = r0;
    *(short8*)(dp + 8) = r1;
}

__device__ __forceinline__ void tconvqkv_body(const float* __restrict__ wq, const float* __restrict__ wk,
                                              const float* __restrict__ wv, u16* __restrict__ dst,
                                              int z, int yy, u16 (*t)[72], int tid)
{
    int w = z >> 4, hh = z & 15;
    const float* src = (w == 0 ? wq : (w == 1 ? wk : wv)) + (size_t)hh * E_ * D_;
    u16* d = dst + (size_t)w * E_ * E_ + (size_t)hh * D_ * E_;
    int k0 = yy * 64;
    int kr = tid >> 4, nc = (tid & 15) * 4;
#pragma unroll
    for (int i = 0; i < 4; i++) {
        f32x4 v = *(const f32x4*)(src + (size_t)(k0 + kr + i * 16) * D_ + nc);
#pragma unroll
        for (int j = 0; j < 4; j++) t[kr + i * 16][nc + j] = f2bf(v[j]);
    }
    __syncthreads();
    int nr = tid >> 2, kg = (tid & 3) * 16;
    short8 r0, r1;
#pragma unroll
    for (int j = 0; j < 8; j++) { r0[j] = (short)t[kg + j][nr]; r1[j] = (short)t[kg + 8 + j][nr]; }
    u16* dp = d + (size_t)nr * E_ + k0 + kg;
    *(short8*)(dp) = r0;
    *(short8*)(dp + 8) = r1;
}

__device__ __forceinline__ void maskprep_body(const int* __restrict__ mask, float* __restrict__ fb,
                                              int* __restrict__ ok, int b, int tid, unsigned char* fl)
{
    int base = tid * 8;
    unsigned all = 1;
#pragma unroll
    for (int j = 0; j < 8; j++) {
        int m = mask[b * S_ + base + j];
        fb[b * S_ + base + j] = m ? 0.f : -1e9f;
        all &= (m != 0) ? 1u : 0u;
    }
    fl[tid] = (unsigned char)all;
    __syncthreads();
    if (tid < 32) {
        unsigned a = 1;
#pragma unroll
        for (int j = 0; j < 8; j++) a &= fl[tid * 8 + j];
        ok[b * 32 + tid] = (int)a;
    }
}

template<int INF32>
__device__ __forceinline__ void ln_body(const void* __restrict__ xv, const float* __restrict__ g,
                                        const float* __restrict__ be, u16* __restrict__ y,
                                        int blk, int tid)
{
    int lane = tid & 63, wave = tid >> 6;
    int row = blk * 4 + wave;
    int c0 = lane * 16;
    float v[16];
    if (INF32) {
        const float* xr = (const float*)xv + (size_t)row * E_ + c0;
#pragma unroll
        for (int i = 0; i < 4; i++) {
            f32x4 xx = *(const f32x4*)(xr + i * 4);
#pragma unroll
            for (int j = 0; j < 4; j++) v[i * 4 + j] = xx[j];
        }
    } else {
        const u16* xr = (const u16*)xv + (size_t)row * E_ + c0;
        short8 a = *(const short8*)(xr);
        short8 b = *(const short8*)(xr + 8);
#pragma unroll
        for (int j = 0; j < 8; j++) { v[j] = bf2f((u16)a[j]); v[8 + j] = bf2f((u16)b[j]); }
    }
    float s = 0.f, q = 0.f;
#pragma unroll
    for (int i = 0; i < 16; i++) { s += v[i]; q += v[i] * v[i]; }
#pragma unroll
    for (int off = 1; off < 64; off <<= 1) {
        s += __shfl_xor(s, off, 64);
        q += __shfl_xor(q, off, 64);
    }
    float mu = s * (1.0f / E_);
    float var = q * (1.0f / E_) - mu * mu;
    float rstd = rsqrtf(var + 1e-5f);
    u16* yr = y + (size_t)row * E_ + c0;
    short8 o0, o1;
#pragma unroll
    for (int j = 0; j < 8; j++) {
        o0[j] = (short)f2bf((v[j] - mu) * rstd * g[c0 + j] + be[c0 + j]);
        o1[j] = (short)f2bf((v[8 + j] - mu) * rstd * g[c0 + 8 + j] + be[c0 + 8 + j]);
    }
    *(short8*)(yr) = o0;
    *(short8*)(yr + 8) = o1;
}

// One launch for all independent prepasses (was 7 dispatches).
__global__ __launch_bounds__(256) void prep_k(
    const float* __restrict__ I, u16* __restrict__ Ibf,
    const float* __restrict__ wq, const float* __restrict__ wk,
    const float* __restrict__ wv, u16* __restrict__ WTqkv,
    const float* __restrict__ w_proj, u16* __restrict__ WTproj,
    const float* __restrict__ w1, u16* __restrict__ WT1,
    const float* __restrict__ w2, u16* __restrict__ WT2,
    const int* __restrict__ mask, float* __restrict__ fbm, int* __restrict__ okm,
    const float* __restrict__ x, const float* __restrict__ g1,
    const float* __restrict__ be1, u16* __restrict__ xn)
{
    __shared__ __align__(16) u16 tsh[64][72];
    int id = blockIdx.x, tid = threadIdx.x;
    if (id < 1024) {
        ln_body<1>(x, g1, be1, xn, id, tid);
    } else if (id < 3072) {
        convf_body(I, Ibf, id - 1024, tid);
    } else if (id < 3840) {
        int vb = id - 3072;
        tconvqkv_body(wq, wk, wv, WTqkv, vb >> 4, vb & 15, tsh, tid);
    } else if (id < 4096) {
        int vb = id - 3840;
        tconv_body(w_proj, WTproj, E_, E_, vb & 15, vb >> 4, tsh, tid);
    } else if (id < 5120) {
        int vb = id - 4096;
        tconv_body(w1, WT1, E_, 4 * E_, vb & 63, vb >> 6, tsh, tid);
    } else if (id < 6144) {
        int vb = id - 5120;
        tconv_body(w2, WT2, 4 * E_, E_, vb & 15, vb >> 4, tsh, tid);
    } else {
        maskprep_body(mask, fbm, okm, id - 6144, tid, (unsigned char*)tsh);
    }
}

// ---------------- V transpose: V [B,S,H*64] -> Vt [B,H,64,S] ----------------
__global__ __launch_bounds__(256) void vtrans_k(const u16* __restrict__ V, u16* __restrict__ Vt)
{
    __shared__ u16 t[64][72];
    int s0 = blockIdx.x * 64, h = blockIdx.y, b = blockIdx.z;
    int tid = threadIdx.x;
    int sr = tid >> 2, dc = (tid & 3) * 16;
    const u16* src = V + (size_t)b * S_ * E_ + (size_t)(s0 + sr) * E_ + h * D_ + dc;
    short8 v0 = *(const short8*)(src);
    short8 v1 = *(const short8*)(src + 8);
#pragma unroll
    for (int j = 0; j < 8; j++) { t[sr][dc + j] = v0[j]; t[sr][dc + 8 + j] = v1[j]; }
    __syncthreads();
    int dr = tid >> 2, sc = (tid & 3) * 16;
    short8 r0, r1;
#pragma unroll
    for (int j = 0; j < 8; j++) { r0[j] = (short)t[sc + j][dr]; r1[j] = (short)t[sc + 8 + j][dr]; }
    u16* dp = Vt + ((size_t)(b * H_ + h) * D_ + dr) * S_ + s0 + sc;
    *(short8*)(dp) = r0;
    *(short8*)(dp + 8) = r1;
}

// ---------------- LayerNorm (standalone, used for ln2) ----------------
template<int INF32>
__global__ __launch_bounds__(256) void ln_kernel(
    const void* __restrict__ xv, const float* __restrict__ g,
    const float* __restrict__ be, u16* __restrict__ y)
{
    ln_body<INF32>(xv, g, be, y, blockIdx.x, threadIdx.x);
}

// ---------------- 128x256 BK=32 GEMM, 2 blocks/CU (inter-block overlap) ----------------
// Replaces gemm8p (R2-R6: 3 schedule variants all stuck at ~600 TF / 22% MfmaUtil).
// Diagnosis: 1 block/CU + barrier lockstep serializes LDS-read drain against MFMA
// (2 waves/SIMD all in the same sub-phase). Fix = m114 mechanism: 2 independent
// blocks per CU so one block's MFMA covers the other's staging/drain.
//  - acc[4][4] = 64 VGPR; __launch_bounds__(512,4) caps VGPR at 128 -> 2 blocks/CU.
//  - LDS 48 KB (A 128x32 x2buf + B 256x32 x2buf).
//  - Minimal 2-phase tile loop (catalog T3 recipe): stage(next,obuf) -> 8 ds_read +
//    16 MFMA -> vmcnt(0) -> one barrier. Race ledger: every ds_read feeds a
//    pre-barrier MFMA (compiler lgkm-drains before use), so reads complete before
//    barrier arrival; staging targets the other buffer.
//  - Swizzle for 64B rows: chunk g stored at slot g^((row>>1)&3); read offset
//    collapses to quad^((l16>>1)&3) for ALL fragments; banks tile 32 banks exactly
//    2x (2-way = free, m136). Gload source pre-swizzled, LDS dest linear (rule #21).
template<int QKV, int GELU, int RX>
__global__ __launch_bounds__(512, 4) void gemmb32_k(
    const u16* __restrict__ A, const u16* __restrict__ Axn,
    const u16* __restrict__ WT,
    const float* __restrict__ bq, const float* __restrict__ bk, const float* __restrict__ bv,
    u16* __restrict__ C, int M, int N, int K)
{
    __shared__ __align__(16) short As[2][128 * 32];
    __shared__ __align__(16) short Bs[2][256 * 32];
    int tid = threadIdx.x;
    int wave = tid >> 6, lane = tid & 63, quad = lane >> 4, l16 = lane & 15;
    int wm = wave >> 2, wn = wave & 3;

    // XCD-aware bijective swizzle
    int gx = gridDim.x, gy = gridDim.y;
    int lin = blockIdx.y * gx + blockIdx.x;
    int xcd = lin & 7, w = lin >> 3;
    int rw = gx / RX, rh = gy / (8 / RX);
    int bx = (xcd % RX) * rw + (w % rw);
    int by = (xcd / RX) * rh + (w / rw);
    int n0 = bx * 256, m0 = by * 128;

    int which = QKV ? (n0 >> 10) : 0;
    const u16* Ause = (QKV && which) ? Axn : A;
    const float* bias = QKV ? (which == 0 ? bq : (which == 1 ? bk : bv)) : bq;

    f32x4 acc[4][4];
#pragma unroll
    for (int mi = 0; mi < 4; mi++)
#pragma unroll
        for (int ni = 0; ni < 4; ni++)
            acc[mi][ni] = (f32x4){0.f, 0.f, 0.f, 0.f};

    // staging: A: wave stages rows [w*16,w*16+16) (1 gload); B: rows [w*32,+32) (2 gloads).
    int srow = lane >> 2, slot = lane & 3;
    int kap = (srow >> 1) & 3;
    const u16* Ag = Ause + (size_t)(m0 + wave * 16 + srow) * K + ((slot ^ kap) << 3);
    const u16* Bg = WT + (size_t)(n0 + wave * 32 + srow) * K + ((slot ^ kap) << 3);
    const size_t r16K = (size_t)16 * K;
    int wA = wave * 512, wB = wave * 1024;
    int so = (quad ^ ((l16 >> 1) & 3)) << 3;
    int aoff = (wm * 64 + l16) * 32 + so;
    int boff = (wn * 64 + l16) * 32 + so;
    int NT = K >> 5;

#define STAGEK(BUF, PA, PB) do { \
    gl_lds16((PA), &As[BUF][wA]); \
    gl_lds16((PB), &Bs[BUF][wB]); \
    gl_lds16((PB) + r16K, &Bs[BUF][wB + 512]); } while (0)

#define TILEK(BUF, OBUF, TT, PA, PB) do { \
    if ((TT) + 1 < NT) STAGEK(OBUF, (PA), (PB)); \
    short8 af[4], bf[4]; \
    const short* ab = &As[BUF][aoff]; \
    const short* bb = &Bs[BUF][boff]; \
    _Pragma("unroll") for (int i_ = 0; i_ < 4; i_++) af[i_] = *(const short8*)(ab + i_ * 512); \
    _Pragma("unroll") for (int i_ = 0; i_ < 4; i_++) bf[i_] = *(const short8*)(bb + i_ * 512); \
    _Pragma("unroll") for (int mi = 0; mi < 4; mi++) \
    _Pragma("unroll") for (int ni = 0; ni < 4; ni++) \
        acc[mi][ni] = __builtin_amdgcn_mfma_f32_16x16x32_bf16(af[mi], bf[ni], acc[mi][ni], 0, 0, 0); \
    asm volatile("s_waitcnt vmcnt(0)" ::: "memory"); \
    __builtin_amdgcn_s_barrier(); } while (0)

    // prologue: tile 0
    STAGEK(0, Ag, Bg);
    asm volatile("s_waitcnt vmcnt(0)" ::: "memory");
    __builtin_amdgcn_s_barrier();

    const u16* PA = Ag + 32;
    const u16* PB = Bg + 32;
    for (int t = 0; t < NT; t += 2) {
        TILEK(0, 1, t, PA, PB);
        TILEK(1, 0, t + 1, PA + 32, PB + 32);
        PA += 64; PB += 64;
    }

    u16* Cw = QKV ? (C + (size_t)which * (size_t)M * 1024) : C;
    int ostride = QKV ? 1024 : N;
#pragma unroll
    for (int mi = 0; mi < 4; mi++) {
#pragma unroll
        for (int ni = 0; ni < 4; ni++) {
            int colg = n0 + wn * 64 + ni * 16 + l16;
            int col = QKV ? (colg & 1023) : colg;
            float bb = bias[col];
#pragma unroll
            for (int r = 0; r < 4; r++) {
                int row = m0 + wm * 64 + mi * 16 + quad * 4 + r;
                float v = acc[mi][ni][r] + bb;
                if (QKV && which == 0) v *= 0.03125f;   // fold attention 1/sqrt(E)
                if (GELU) v = 0.5f * v * (1.0f + erff(v * 0.70710678118f));
                Cw[(size_t)row * ostride + col] = f2bf(v);
            }
        }
    }
#undef STAGEK
#undef TILEK
}

// ---------------- split-K GEMM BK=64: bf16 partials (+XCD swizzle) ----------------
__global__ __launch_bounds__(256) void gemmsk_k(
    const u16* __restrict__ A, const u16* __restrict__ WT,
    u16* __restrict__ P, int M, int N, int K, int Ks)
{
    __shared__ __align__(16) short a_sh[2][128 * 32];
    __shared__ __align__(16) short b_sh[2][128 * 32];
    int tid = threadIdx.x;
    int wave = tid >> 6, lane = tid & 63, quad = lane >> 4, l16 = lane & 15;
    int wm = wave >> 1, wn = wave & 1;
    int gx = gridDim.x;
    int lin = blockIdx.y * gx + blockIdx.x;
    int xcd = lin & 7, w = lin >> 3;
    int rh = gridDim.y >> 3;
    int bx = w % gx, by = xcd * rh + (w / gx);
    int m0 = by * 128, n0 = bx * 128;
    int koff = blockIdx.z * Ks;

    f32x4 acc[4][4];
#pragma unroll
    for (int mt = 0; mt < 4; mt++)
#pragma unroll
        for (int nt = 0; nt < 4; nt++)
            acc[mt][nt] = (f32x4){0.f, 0.f, 0.f, 0.f};

    int srow = lane >> 2;
    int c = ((lane & 3) ^ ((lane >> 3) & 3)) * 8;
    const u16* Ab = A + (size_t)(m0 + wave * 32 + srow) * K + koff + c;
    const u16* Bb = WT + (size_t)(n0 + wave * 32 + srow) * K + koff + c;
    short* al0 = &a_sh[0][wave * 1024];
    short* al1 = &a_sh[1][wave * 1024];
    short* bl0 = &b_sh[0][wave * 1024];
    short* bl1 = &b_sh[1][wave * 1024];
    int xo = (quad ^ ((l16 >> 1) & 3)) * 8;

    for (int kk = 0; kk < Ks; kk += 64) {
        __syncthreads();
        gl_lds16(Ab + kk, al0);
        gl_lds16(Ab + kk + (size_t)16 * K, al0 + 512);
        gl_lds16(Ab + kk + 32, al1);
        gl_lds16(Ab + kk + (size_t)16 * K + 32, al1 + 512);
        gl_lds16(Bb + kk, bl0);
        gl_lds16(Bb + kk + (size_t)16 * K, bl0 + 512);
        gl_lds16(Bb + kk + 32, bl1);
        gl_lds16(Bb + kk + (size_t)16 * K + 32, bl1 + 512);
        __syncthreads();

#pragma unroll
        for (int h = 0; h < 2; h++) {
            short8 af[4], bf8[4];
#pragma unroll
            for (int mt = 0; mt < 4; mt++)
                af[mt] = *(const short8*)(&a_sh[h][(wm * 64 + mt * 16 + l16) * 32 + xo]);
#pragma unroll
            for (int nt = 0; nt < 4; nt++)
                bf8[nt] = *(const short8*)(&b_sh[h][(wn * 64 + nt * 16 + l16) * 32 + xo]);
#pragma unroll
            for (int mt = 0; mt < 4; mt++)
#pragma unroll
                for (int nt = 0; nt < 4; nt++)
                    acc[mt][nt] = __builtin_amdgcn_mfma_f32_16x16x32_bf16(af[mt], bf8[nt], acc[mt][nt], 0, 0, 0);
        }
    }

    u16* Pz = P + (size_t)blockIdx.z * (size_t)M * N;
#pragma unroll
    for (int mt = 0; mt < 4; mt++) {
#pragma unroll
        for (int nt = 0; nt < 4; nt++) {
            int col = n0 + wn * 64 + nt * 16 + l16;
#pragma unroll
            for (int r = 0; r < 4; r++) {
                int row = m0 + wm * 64 + mt * 16 + quad * 4 + r;
                Pz[(size_t)row * N + col] = f2bf(acc[mt][nt][r]);
            }
        }
    }
}

// ---------------- combine 2 bf16 partials + bias + residual -> f32 out ----------------
__global__ __launch_bounds__(256) void combine2_k(
    const u16* __restrict__ P, const float* __restrict__ bias,
    const u16* __restrict__ res, float* __restrict__ out)
{
    const size_t MN = (size_t)TOK * E_;
    size_t i = ((size_t)blockIdx.x * 256 + threadIdx.x) * 8;
    int col = (int)(i & (E_ - 1));
    float v[8];
    f32x4 b0 = *(const f32x4*)(bias + col);
    f32x4 b1 = *(const f32x4*)(bias + col + 4);
    short8 rr = *(const short8*)(res + i);
#pragma unroll
    for (int j = 0; j < 4; j++) { v[j] = b0[j] + bf2f((u16)rr[j]); v[4 + j] = b1[j] + bf2f((u16)rr[4 + j]); }
#pragma unroll
    for (int z = 0; z < 2; z++) {
        short8 p = *(const short8*)(P + z * MN + i);
#pragma unroll
        for (int j = 0; j < 8; j++) v[j] += bf2f((u16)p[j]);
    }
    f32x4 o0, o1;
#pragma unroll
    for (int j = 0; j < 4; j++) { o0[j] = v[j]; o1[j] = v[4 + j]; }
    *(f32x4*)(out + i) = o0;
    *(f32x4*)(out + i + 4) = o1;
}

// ---------------- 128x64 bf16 GEMM BK=64 for N=1024 shapes ----------------
template<int GELU, int RES, int CF32>
__global__ __launch_bounds__(256) void gemm3_k(
    const u16* __restrict__ A, const u16* __restrict__ WT,
    const float* __restrict__ bias, const u16* __restrict__ res,
    void* __restrict__ Cv, int M, int N, int K)
{
    __shared__ __align__(16) short a_sh[2][128 * 32];
    __shared__ __align__(16) short b_sh[2][64 * 32];
    int tid = threadIdx.x;
    int wave = tid >> 6, lane = tid & 63, quad = lane >> 4, l16 = lane & 15;
    int wm = wave >> 1, wn = wave & 1;
    int m0 = blockIdx.y * 128, n0 = blockIdx.x * 64;

    f32x4 acc[4][2];
#pragma unroll
    for (int mt = 0; mt < 4; mt++)
#pragma unroll
        for (int nt = 0; nt < 2; nt++)
            acc[mt][nt] = (f32x4){0.f, 0.f, 0.f, 0.f};

    int srow = lane >> 2;
    int c = ((lane & 3) ^ ((lane >> 3) & 3)) * 8;
    const u16* Ab = A + (size_t)(m0 + wave * 32 + srow) * K + c;
    const u16* Bb = WT + (size_t)(n0 + wave * 16 + srow) * K + c;
    short* al0 = &a_sh[0][wave * 1024];
    short* al1 = &a_sh[1][wave * 1024];
    short* bl0 = &b_sh[0][wave * 512];
    short* bl1 = &b_sh[1][wave * 512];
    int xo = (quad ^ ((l16 >> 1) & 3)) * 8;

    for (int kk = 0; kk < K; kk += 64) {
        __syncthreads();
        gl_lds16(Ab + kk, al0);
        gl_lds16(Ab + kk + (size_t)16 * K, al0 + 512);
        gl_lds16(Ab + kk + 32, al1);
        gl_lds16(Ab + kk + (size_t)16 * K + 32, al1 + 512);
        gl_lds16(Bb + kk, bl0);
        gl_lds16(Bb + kk + 32, bl1);
        __syncthreads();

#pragma unroll
        for (int h = 0; h < 2; h++) {
            short8 af[4], bf8[2];
#pragma unroll
            for (int mt = 0; mt < 4; mt++)
                af[mt] = *(const short8*)(&a_sh[h][(wm * 64 + mt * 16 + l16) * 32 + xo]);
#pragma unroll
            for (int nt = 0; nt < 2; nt++)
                bf8[nt] = *(const short8*)(&b_sh[h][(wn * 32 + nt * 16 + l16) * 32 + xo]);
#pragma unroll
            for (int mt = 0; mt < 4; mt++)
#pragma unroll
                for (int nt = 0; nt < 2; nt++)
                    acc[mt][nt] = __builtin_amdgcn_mfma_f32_16x16x32_bf16(af[mt], bf8[nt], acc[mt][nt], 0, 0, 0);
        }
    }

#pragma unroll
    for (int mt = 0; mt < 4; mt++) {
#pragma unroll
        for (int nt = 0; nt < 2; nt++) {
            int col = n0 + wn * 32 + nt * 16 + l16;
            float bb = bias[col];
#pragma unroll
            for (int r = 0; r < 4; r++) {
                int row = m0 + wm * 64 + mt * 16 + quad * 4 + r;
                float v = acc[mt][nt][r] + bb;
                if (RES) v += bf2f(res[(size_t)row * N + col]);
                if (GELU) v = 0.5f * v * (1.0f + erff(v * 0.70710678118f));
                if (CF32) ((float*)Cv)[(size_t)row * N + col] = v;
                else ((u16*)Cv)[(size_t)row * N + col] = f2bf(v);
            }
        }
    }
}

// ---------------- Flash attention v4 + XCD head-grouping (R6 frozen) ----------------
__global__ __launch_bounds__(512) void attn_k(
    const u16* __restrict__ Q, const u16* __restrict__ K,
    const u16* __restrict__ Vt, const float* __restrict__ fb,
    const int* __restrict__ ok, u16* __restrict__ O)
{
    __shared__ __align__(16) short k_sh[2][2][64 * 32];  // [buf][d-half][key][32]
    __shared__ __align__(16) short v_sh[2][2][64 * 32];  // [buf][key-half][d][32]
    __shared__ __align__(16) short p_sh[8][16 * 72];     // per-wave P^T [q][key]
    int tid = threadIdx.x;
    int wave = tid >> 6, lane = tid & 63, quad = lane >> 4, l16 = lane & 15;
    int lin = blockIdx.x + 16 * (blockIdx.y + 16 * blockIdx.z);
    int xcd = lin & 7, w = lin >> 3;
    int combo = xcd * 4 + (w >> 4);
    int qb = w & 15, h = combo & 15, b = combo >> 4;
    int q0 = qb * 128;
    const u16* Qp = Q + (size_t)b * S_ * E_ + (size_t)h * D_;
    const u16* Kp = K + (size_t)b * S_ * E_ + (size_t)h * D_;
    const u16* Vtp = Vt + (size_t)(b * H_ + h) * D_ * S_;

    int qrow = q0 + wave * 16 + l16;
    short8 qf0 = *(const short8*)(Qp + (size_t)qrow * E_ + quad * 8);
    short8 qf1 = *(const short8*)(Qp + (size_t)qrow * E_ + 32 + quad * 8);

    f32x4 o[4];
#pragma unroll
    for (int dt = 0; dt < 4; dt++) o[dt] = (f32x4){0.f, 0.f, 0.f, 0.f};
    float rs_tot = 0.f;

    int sub = wave & 1, rblk = wave >> 1;
    int srow = lane >> 2;
    int c = ((lane & 3) ^ ((lane >> 3) & 3)) * 8;
    const u16* Kg = Kp + (size_t)(rblk * 16 + srow) * E_ + sub * 32 + c;
    const u16* Vg = Vtp + (size_t)(rblk * 16 + srow) * S_ + sub * 32 + c;
    short* kl0 = &k_sh[0][sub][rblk * 512];
    short* kl1 = &k_sh[1][sub][rblk * 512];
    short* vl0 = &v_sh[0][sub][rblk * 512];
    short* vl1 = &v_sh[1][sub][rblk * 512];

    gl_lds16(Kg, kl0);
    gl_lds16(Vg, vl0);
    __syncthreads();

    const float* fbb = fb + b * S_;
    const int* okb = ok + b * 32;
    int xo = (quad ^ ((l16 >> 1) & 3)) * 8;

    for (int kt = 0; kt < S_ / 64; kt++) {
        int cur = kt & 1;
        if (kt < 31) {
            gl_lds16(Kg + (size_t)(kt + 1) * 64 * E_, cur ? kl0 : kl1);
            gl_lds16(Vg + (kt + 1) * 64, cur ? vl0 : vl1);
        }

        f32x4 s[4];
#pragma unroll
        for (int mt = 0; mt < 4; mt++) {
            int ro = (mt * 16 + l16) * 32 + xo;
            short8 kf0 = *(const short8*)(&k_sh[cur][0][ro]);
            short8 kf1 = *(const short8*)(&k_sh[cur][1][ro]);
            s[mt] = __builtin_amdgcn_mfma_f32_16x16x32_bf16(kf0, qf0, (f32x4){0.f,0.f,0.f,0.f}, 0, 0, 0);
            s[mt] = __builtin_amdgcn_mfma_f32_16x16x32_bf16(kf1, qf1, s[mt], 0, 0, 0);
        }

        if (!okb[kt]) {
#pragma unroll
            for (int mt = 0; mt < 4; mt++)
#pragma unroll
                for (int r = 0; r < 4; r++)
                    s[mt][r] += fbb[kt * 64 + mt * 16 + quad * 4 + r];
        }

#pragma unroll
        for (int mt = 0; mt < 4; mt++) {
            float p0 = __expf(s[mt][0]);
            float p1 = __expf(s[mt][1]);
            float p2 = __expf(s[mt][2]);
            float p3 = __expf(s[mt][3]);
            rs_tot += (p0 + p1) + (p2 + p3);
            u32 u0 = __builtin_amdgcn_perm(fbits(p1), fbits(p0), 0x07060302u);
            u32 u1 = __builtin_amdgcn_perm(fbits(p3), fbits(p2), 0x07060302u);
            uint2 pk; pk.x = u0; pk.y = u1;
            *(uint2*)(&p_sh[wave][l16 * 72 + mt * 16 + quad * 4]) = pk;
        }

#pragma unroll
        for (int sk = 0; sk < 2; sk++) {
            short8 pf = *(const short8*)(&p_sh[wave][l16 * 72 + sk * 32 + quad * 8]);
#pragma unroll
            for (int dt = 0; dt < 4; dt++) {
                short8 vf = *(const short8*)(&v_sh[cur][sk][(dt * 16 + l16) * 32 + xo]);
                o[dt] = __builtin_amdgcn_mfma_f32_16x16x32_bf16(vf, pf, o[dt], 0, 0, 0);
            }
        }
        __syncthreads();
    }

    rs_tot += __shfl_xor(rs_tot, 16, 64);
    rs_tot += __shfl_xor(rs_tot, 32, 64);
    float inv = 1.0f / rs_tot;
    u16* Op = O + (size_t)b * S_ * E_ + (size_t)(q0 + wave * 16 + l16) * E_ + h * D_;
#pragma unroll
    for (int dt = 0; dt < 4; dt++) {
        short4_t pk;
#pragma unroll
        for (int r = 0; r < 4; r++) pk[r] = (short)f2bf(o[dt][r] * inv);
        *(short4_t*)(Op + dt * 16 + quad * 4) = pk;
    }
}

extern "C" void kernel_launch(void* const* d_in, const int* in_sizes, int n_in,
                              void* d_out, int out_size, void* d_ws, size_t ws_size,
                              hipStream_t stream)
{
    (void)in_sizes; (void)n_in; (void)out_size; (void)ws_size;
    const float* I      = (const float*)d_in[0];
    const float* x      = (const float*)d_in[1];
    const int*   mask   = (const int*)d_in[2];
    const float* wq     = (const float*)d_in[3];
    const float* bq     = (const float*)d_in[4];
    const float* wk     = (const float*)d_in[5];
    const float* bk     = (const float*)d_in[6];
    const float* wv     = (const float*)d_in[7];
    const float* bv     = (const float*)d_in[8];
    const float* w_proj = (const float*)d_in[9];
    const float* b_proj = (const float*)d_in[10];
    const float* g1     = (const float*)d_in[11];
    const float* be1    = (const float*)d_in[12];
    const float* g2     = (const float*)d_in[13];
    const float* be2    = (const float*)d_in[14];
    const float* w1     = (const float*)d_in[15];
    const float* b1     = (const float*)d_in[16];
    const float* w2     = (const float*)d_in[17];
    const float* b2     = (const float*)d_in[18];
    float* out = (float*)d_out;

    char* ws = (char*)d_ws;
    const size_t SZ = (size_t)TOK * E_;
    u16* xn   = (u16*)(ws);
    u16* qb_  = (u16*)(ws + SZ * 2);
    u16* kb_  = (u16*)(ws + SZ * 4);
    u16* vb_  = (u16*)(ws + SZ * 6);
    u16* Vt   = (u16*)(ws + SZ * 8);
    u16* Ibf  = (u16*)(ws + SZ * 8);
    u16* ctx  = (u16*)(ws + SZ * 6);
    u16* hb   = (u16*)(ws + SZ * 4);
    u16* h2   = (u16*)(ws);
    u16* a1   = (u16*)(ws + SZ * 2);
    u16* WTqkv  = (u16*)(ws + 40u * 1024 * 1024);
    u16* WTproj = (u16*)(ws + 46u * 1024 * 1024);
    u16* WT1    = (u16*)(ws + 48u * 1024 * 1024);
    u16* WT2    = (u16*)(ws + 56u * 1024 * 1024);
    u16* Pp     = (u16*)(ws + 40u * 1024 * 1024);
    float* fbm  = (float*)(ws + 40u * 1024 * 1024);
    int*   okm  = (int*)(ws + 40u * 1024 * 1024 + 16384);

    // Fused prepass: ln1 + convf + all 4 weight transposes + maskprep in ONE launch.
    prep_k<<<dim3(6146), 256, 0, stream>>>(
        I, Ibf, wq, wk, wv, WTqkv, w_proj, WTproj, w1, WT1, w2, WT2,
        mask, fbm, okm, x, g1, be1, xn);

    // QKV: 128x256 BK=32, 2 blocks/CU; grid (12, 32); RX=2
    gemmb32_k<1,0,2><<<dim3(12, TOK / 128), 512, 0, stream>>>(
        Ibf, xn, WTqkv, bq, bk, bv, qb_, TOK, 3072, E_);

    vtrans_k<<<dim3(S_ / 64, H_, B_), 256, 0, stream>>>(vb_, Vt);

    attn_k<<<dim3(S_ / 128, H_, B_), 512, 0, stream>>>(qb_, kb_, Vt, fbm, okm, ctx);

    gemm3_k<0,1,0><<<dim3(16, TOK / 128), 256, 0, stream>>>(
        ctx, WTproj, b_proj, xn, hb, TOK, E_, E_);
    ln_kernel<0><<<TOK / 4, 256, 0, stream>>>(hb, g2, be2, h2);
    // FFN1: 128x256 BK=32, 2 blocks/CU; grid (16, 32); RX=2; fused GELU
    gemmb32_k<0,1,2><<<dim3(16, TOK / 128), 512, 0, stream>>>(
        h2, nullptr, WT1, b1, nullptr, nullptr, a1, TOK, 4 * E_, E_);
    gemmsk_k<<<dim3(8, TOK / 128, 2), 256, 0, stream>>>(
        a1, WT2, Pp, TOK, E_, 4 * E_, 2 * E_);
    combine2_k<<<dim3(TOK * E_ / (256 * 8)), 256, 0, stream>>>(Pp, b2, h2, out);
}

// Round 9
// 349.478 us; speedup vs baseline: 1.0686x; 1.0221x over previous
//
#include <hip/hip_runtime.h>
#include <hip/hip_bf16.h>
#include <math.h>

typedef short short8 __attribute__((ext_vector_type(8)));
typedef short short4_t __attribute__((ext_vector_type(4)));
typedef float f32x4 __attribute__((ext_vector_type(4)));
typedef unsigned short u16;
typedef unsigned int u32;

#define B_ 2
#define S_ 2048
#define E_ 1024
#define H_ 16
#define D_ 64
#define TOK (B_*S_)

#if __has_builtin(__builtin_amdgcn_exp2f)
#define EXP2F(x) __builtin_amdgcn_exp2f(x)
#else
#define EXP2F(x) exp2f(x)
#endif

__device__ __forceinline__ float bf2f(u16 u) {
    union { unsigned int u; float f; } v; v.u = ((unsigned int)u) << 16; return v.f;
}
__device__ __forceinline__ u16 f2bf(float f) {
    union { float f; unsigned int u; } v; v.f = f;
    unsigned int r = v.u + 0x7fffu + ((v.u >> 16) & 1u);
    return (u16)(r >> 16);
}
__device__ __forceinline__ u32 fbits(float f) {
    union { float f; u32 u; } v; v.f = f; return v.u;
}
__device__ __forceinline__ void gl_lds16(const u16* g, short* l) {
    __builtin_amdgcn_global_load_lds(
        (const __attribute__((address_space(1))) unsigned int*)(g),
        (__attribute__((address_space(3))) unsigned int*)(l), 16, 0, 0);
}

// ================= fused prepass bodies =================

__device__ __forceinline__ void convf_body(const float* __restrict__ s, u16* __restrict__ d,
                                           int blk, int tid)
{
    size_t i = ((size_t)blk * 256 + tid) * 8;
    f32x4 a = *(const f32x4*)(s + i);
    f32x4 b = *(const f32x4*)(s + i + 4);
    short8 r;
#pragma unroll
    for (int j = 0; j < 4; j++) { r[j] = (short)f2bf(a[j]); r[4 + j] = (short)f2bf(b[j]); }
    *(short8*)(d + i) = r;
}

__device__ __forceinline__ void tconv_body(const float* __restrict__ src, u16* __restrict__ dst,
                                           int K, int N, int bx, int by, u16 (*t)[72], int tid)
{
    int k0 = by * 64, n0 = bx * 64;
    int kr = tid >> 4, nc = (tid & 15) * 4;
#pragma unroll
    for (int i = 0; i < 4; i++) {
        f32x4 v = *(const f32x4*)(src + (size_t)(k0 + kr + i * 16) * N + n0 + nc);
#pragma unroll
        for (int j = 0; j < 4; j++) t[kr + i * 16][nc + j] = f2bf(v[j]);
    }
    __syncthreads();
    int nr = tid >> 2, kg = (tid & 3) * 16;
    short8 r0, r1;
#pragma unroll
    for (int j = 0; j < 8; j++) { r0[j] = (short)t[kg + j][nr]; r1[j] = (short)t[kg + 8 + j][nr]; }
    u16* dp = dst + (size_t)(n0 + nr) * K + k0 + kg;
    *(short8*)(dp) = r0;
    *(short8*)(dp + 8) = r1;
}

__device__ __forceinline__ void tconvqkv_body(const float* __restrict__ wq, const float* __restrict__ wk,
                                              const float* __restrict__ wv, u16* __restrict__ dst,
                                              int z, int yy, u16 (*t)[72], int tid)
{
    int w = z >> 4, hh = z & 15;
    const float* src = (w == 0 ? wq : (w == 1 ? wk : wv)) + (size_t)hh * E_ * D_;
    u16* d = dst + (size_t)w * E_ * E_ + (size_t)hh * D_ * E_;
    int k0 = yy * 64;
    int kr = tid >> 4, nc = (tid & 15) * 4;
#pragma unroll
    for (int i = 0; i < 4; i++) {
        f32x4 v = *(const f32x4*)(src + (size_t)(k0 + kr + i * 16) * D_ + nc);
#pragma unroll
        for (int j = 0; j < 4; j++) t[kr + i * 16][nc + j] = f2bf(v[j]);
    }
    __syncthreads();
    int nr = tid >> 2, kg = (tid & 3) * 16;
    short8 r0, r1;
#pragma unroll
    for (int j = 0; j < 8; j++) { r0[j] = (short)t[kg + j][nr]; r1[j] = (short)t[kg + 8 + j][nr]; }
    u16* dp = d + (size_t)nr * E_ + k0 + kg;
    *(short8*)(dp) = r0;
    *(short8*)(dp + 8) = r1;
}

__device__ __forceinline__ void maskprep_body(const int* __restrict__ mask, float* __restrict__ fb,
                                              int* __restrict__ ok, int b, int tid, unsigned char* fl)
{
    int base = tid * 8;
    unsigned all = 1;
#pragma unroll
    for (int j = 0; j < 8; j++) {
        int m = mask[b * S_ + base + j];
        fb[b * S_ + base + j] = m ? 0.f : -1e9f;
        all &= (m != 0) ? 1u : 0u;
    }
    fl[tid] = (unsigned char)all;
    __syncthreads();
    if (tid < 32) {
        unsigned a = 1;
#pragma unroll
        for (int j = 0; j < 8; j++) a &= fl[tid * 8 + j];
        ok[b * 32 + tid] = (int)a;
    }
}

template<int INF32>
__device__ __forceinline__ void ln_body(const void* __restrict__ xv, const float* __restrict__ g,
                                        const float* __restrict__ be, u16* __restrict__ y,
                                        int blk, int tid)
{
    int lane = tid & 63, wave = tid >> 6;
    int row = blk * 4 + wave;
    int c0 = lane * 16;
    float v[16];
    if (INF32) {
        const float* xr = (const float*)xv + (size_t)row * E_ + c0;
#pragma unroll
        for (int i = 0; i < 4; i++) {
            f32x4 xx = *(const f32x4*)(xr + i * 4);
#pragma unroll
            for (int j = 0; j < 4; j++) v[i * 4 + j] = xx[j];
        }
    } else {
        const u16* xr = (const u16*)xv + (size_t)row * E_ + c0;
        short8 a = *(const short8*)(xr);
        short8 b = *(const short8*)(xr + 8);
#pragma unroll
        for (int j = 0; j < 8; j++) { v[j] = bf2f((u16)a[j]); v[8 + j] = bf2f((u16)b[j]); }
    }
    float s = 0.f, q = 0.f;
#pragma unroll
    for (int i = 0; i < 16; i++) { s += v[i]; q += v[i] * v[i]; }
#pragma unroll
    for (int off = 1; off < 64; off <<= 1) {
        s += __shfl_xor(s, off, 64);
        q += __shfl_xor(q, off, 64);
    }
    float mu = s * (1.0f / E_);
    float var = q * (1.0f / E_) - mu * mu;
    float rstd = rsqrtf(var + 1e-5f);
    u16* yr = y + (size_t)row * E_ + c0;
    short8 o0, o1;
#pragma unroll
    for (int j = 0; j < 8; j++) {
        o0[j] = (short)f2bf((v[j] - mu) * rstd * g[c0 + j] + be[c0 + j]);
        o1[j] = (short)f2bf((v[8 + j] - mu) * rstd * g[c0 + 8 + j] + be[c0 + 8 + j]);
    }
    *(short8*)(yr) = o0;
    *(short8*)(yr + 8) = o1;
}

// One launch for all independent prepasses (was 7 dispatches).
__global__ __launch_bounds__(256) void prep_k(
    const float* __restrict__ I, u16* __restrict__ Ibf,
    const float* __restrict__ wq, const float* __restrict__ wk,
    const float* __restrict__ wv, u16* __restrict__ WTqkv,
    const float* __restrict__ w_proj, u16* __restrict__ WTproj,
    const float* __restrict__ w1, u16* __restrict__ WT1,
    const float* __restrict__ w2, u16* __restrict__ WT2,
    const int* __restrict__ mask, float* __restrict__ fbm, int* __restrict__ okm,
    const float* __restrict__ x, const float* __restrict__ g1,
    const float* __restrict__ be1, u16* __restrict__ xn)
{
    __shared__ __align__(16) u16 tsh[64][72];
    int id = blockIdx.x, tid = threadIdx.x;
    if (id < 1024) {
        ln_body<1>(x, g1, be1, xn, id, tid);
    } else if (id < 3072) {
        convf_body(I, Ibf, id - 1024, tid);
    } else if (id < 3840) {
        int vb = id - 3072;
        tconvqkv_body(wq, wk, wv, WTqkv, vb >> 4, vb & 15, tsh, tid);
    } else if (id < 4096) {
        int vb = id - 3840;
        tconv_body(w_proj, WTproj, E_, E_, vb & 15, vb >> 4, tsh, tid);
    } else if (id < 5120) {
        int vb = id - 4096;
        tconv_body(w1, WT1, E_, 4 * E_, vb & 63, vb >> 6, tsh, tid);
    } else if (id < 6144) {
        int vb = id - 5120;
        tconv_body(w2, WT2, 4 * E_, E_, vb & 15, vb >> 4, tsh, tid);
    } else {
        maskprep_body(mask, fbm, okm, id - 6144, tid, (unsigned char*)tsh);
    }
}

// ---------------- V transpose: V [B,S,H*64] -> Vt [B,H,64,S] ----------------
__global__ __launch_bounds__(256) void vtrans_k(const u16* __restrict__ V, u16* __restrict__ Vt)
{
    __shared__ u16 t[64][72];
    int s0 = blockIdx.x * 64, h = blockIdx.y, b = blockIdx.z;
    int tid = threadIdx.x;
    int sr = tid >> 2, dc = (tid & 3) * 16;
    const u16* src = V + (size_t)b * S_ * E_ + (size_t)(s0 + sr) * E_ + h * D_ + dc;
    short8 v0 = *(const short8*)(src);
    short8 v1 = *(const short8*)(src + 8);
#pragma unroll
    for (int j = 0; j < 8; j++) { t[sr][dc + j] = v0[j]; t[sr][dc + 8 + j] = v1[j]; }
    __syncthreads();
    int dr = tid >> 2, sc = (tid & 3) * 16;
    short8 r0, r1;
#pragma unroll
    for (int j = 0; j < 8; j++) { r0[j] = (short)t[sc + j][dr]; r1[j] = (short)t[sc + 8 + j][dr]; }
    u16* dp = Vt + ((size_t)(b * H_ + h) * D_ + dr) * S_ + s0 + sc;
    *(short8*)(dp) = r0;
    *(short8*)(dp + 8) = r1;
}

// ---------------- LayerNorm (standalone, used for ln2) ----------------
template<int INF32>
__global__ __launch_bounds__(256) void ln_kernel(
    const void* __restrict__ xv, const float* __restrict__ g,
    const float* __restrict__ be, u16* __restrict__ y)
{
    ln_body<INF32>(xv, g, be, y, blockIdx.x, threadIdx.x);
}

// ---------------- 128x256 BK=32 GEMM, 2 blocks/CU (R7 frozen) ----------------
// QSCALE for Q-third folds attention 1/sqrt(E) AND log2(e) (attn uses exp2).
template<int QKV, int GELU, int RX>
__global__ __launch_bounds__(512, 4) void gemmb32_k(
    const u16* __restrict__ A, const u16* __restrict__ Axn,
    const u16* __restrict__ WT,
    const float* __restrict__ bq, const float* __restrict__ bk, const float* __restrict__ bv,
    u16* __restrict__ C, int M, int N, int K)
{
    __shared__ __align__(16) short As[2][128 * 32];
    __shared__ __align__(16) short Bs[2][256 * 32];
    int tid = threadIdx.x;
    int wave = tid >> 6, lane = tid & 63, quad = lane >> 4, l16 = lane & 15;
    int wm = wave >> 2, wn = wave & 3;

    int gx = gridDim.x, gy = gridDim.y;
    int lin = blockIdx.y * gx + blockIdx.x;
    int xcd = lin & 7, w = lin >> 3;
    int rw = gx / RX, rh = gy / (8 / RX);
    int bx = (xcd % RX) * rw + (w % rw);
    int by = (xcd / RX) * rh + (w / rw);
    int n0 = bx * 256, m0 = by * 128;

    int which = QKV ? (n0 >> 10) : 0;
    const u16* Ause = (QKV && which) ? Axn : A;
    const float* bias = QKV ? (which == 0 ? bq : (which == 1 ? bk : bv)) : bq;

    f32x4 acc[4][4];
#pragma unroll
    for (int mi = 0; mi < 4; mi++)
#pragma unroll
        for (int ni = 0; ni < 4; ni++)
            acc[mi][ni] = (f32x4){0.f, 0.f, 0.f, 0.f};

    int srow = lane >> 2, slot = lane & 3;
    int kap = (srow >> 1) & 3;
    const u16* Ag = Ause + (size_t)(m0 + wave * 16 + srow) * K + ((slot ^ kap) << 3);
    const u16* Bg = WT + (size_t)(n0 + wave * 32 + srow) * K + ((slot ^ kap) << 3);
    const size_t r16K = (size_t)16 * K;
    int wA = wave * 512, wB = wave * 1024;
    int so = (quad ^ ((l16 >> 1) & 3)) << 3;
    int aoff = (wm * 64 + l16) * 32 + so;
    int boff = (wn * 64 + l16) * 32 + so;
    int NT = K >> 5;

#define STAGEK(BUF, PA, PB) do { \
    gl_lds16((PA), &As[BUF][wA]); \
    gl_lds16((PB), &Bs[BUF][wB]); \
    gl_lds16((PB) + r16K, &Bs[BUF][wB + 512]); } while (0)

#define TILEK(BUF, OBUF, TT, PA, PB) do { \
    if ((TT) + 1 < NT) STAGEK(OBUF, (PA), (PB)); \
    short8 af[4], bf[4]; \
    const short* ab = &As[BUF][aoff]; \
    const short* bb = &Bs[BUF][boff]; \
    _Pragma("unroll") for (int i_ = 0; i_ < 4; i_++) af[i_] = *(const short8*)(ab + i_ * 512); \
    _Pragma("unroll") for (int i_ = 0; i_ < 4; i_++) bf[i_] = *(const short8*)(bb + i_ * 512); \
    _Pragma("unroll") for (int mi = 0; mi < 4; mi++) \
    _Pragma("unroll") for (int ni = 0; ni < 4; ni++) \
        acc[mi][ni] = __builtin_amdgcn_mfma_f32_16x16x32_bf16(af[mi], bf[ni], acc[mi][ni], 0, 0, 0); \
    asm volatile("s_waitcnt vmcnt(0)" ::: "memory"); \
    __builtin_amdgcn_s_barrier(); } while (0)

    STAGEK(0, Ag, Bg);
    asm volatile("s_waitcnt vmcnt(0)" ::: "memory");
    __builtin_amdgcn_s_barrier();

    const u16* PA = Ag + 32;
    const u16* PB = Bg + 32;
    for (int t = 0; t < NT; t += 2) {
        TILEK(0, 1, t, PA, PB);
        TILEK(1, 0, t + 1, PA + 32, PB + 32);
        PA += 64; PB += 64;
    }

    u16* Cw = QKV ? (C + (size_t)which * (size_t)M * 1024) : C;
    int ostride = QKV ? 1024 : N;
#pragma unroll
    for (int mi = 0; mi < 4; mi++) {
#pragma unroll
        for (int ni = 0; ni < 4; ni++) {
            int colg = n0 + wn * 64 + ni * 16 + l16;
            int col = QKV ? (colg & 1023) : colg;
            float bb = bias[col];
#pragma unroll
            for (int r = 0; r < 4; r++) {
                int row = m0 + wm * 64 + mi * 16 + quad * 4 + r;
                float v = acc[mi][ni][r] + bb;
                if (QKV && which == 0) v *= 0.04508422f;   // (1/sqrt(E)) * log2(e): attn uses exp2
                if (GELU) v = 0.5f * v * (1.0f + erff(v * 0.70710678118f));
                Cw[(size_t)row * ostride + col] = f2bf(v);
            }
        }
    }
#undef STAGEK
#undef TILEK
}

// ---------------- split-K GEMM BK=64: bf16 partials (+XCD swizzle) ----------------
__global__ __launch_bounds__(256) void gemmsk_k(
    const u16* __restrict__ A, const u16* __restrict__ WT,
    u16* __restrict__ P, int M, int N, int K, int Ks)
{
    __shared__ __align__(16) short a_sh[2][128 * 32];
    __shared__ __align__(16) short b_sh[2][128 * 32];
    int tid = threadIdx.x;
    int wave = tid >> 6, lane = tid & 63, quad = lane >> 4, l16 = lane & 15;
    int wm = wave >> 1, wn = wave & 1;
    int gx = gridDim.x;
    int lin = blockIdx.y * gx + blockIdx.x;
    int xcd = lin & 7, w = lin >> 3;
    int rh = gridDim.y >> 3;
    int bx = w % gx, by = xcd * rh + (w / gx);
    int m0 = by * 128, n0 = bx * 128;
    int koff = blockIdx.z * Ks;

    f32x4 acc[4][4];
#pragma unroll
    for (int mt = 0; mt < 4; mt++)
#pragma unroll
        for (int nt = 0; nt < 4; nt++)
            acc[mt][nt] = (f32x4){0.f, 0.f, 0.f, 0.f};

    int srow = lane >> 2;
    int c = ((lane & 3) ^ ((lane >> 3) & 3)) * 8;
    const u16* Ab = A + (size_t)(m0 + wave * 32 + srow) * K + koff + c;
    const u16* Bb = WT + (size_t)(n0 + wave * 32 + srow) * K + koff + c;
    short* al0 = &a_sh[0][wave * 1024];
    short* al1 = &a_sh[1][wave * 1024];
    short* bl0 = &b_sh[0][wave * 1024];
    short* bl1 = &b_sh[1][wave * 1024];
    int xo = (quad ^ ((l16 >> 1) & 3)) * 8;

    for (int kk = 0; kk < Ks; kk += 64) {
        __syncthreads();
        gl_lds16(Ab + kk, al0);
        gl_lds16(Ab + kk + (size_t)16 * K, al0 + 512);
        gl_lds16(Ab + kk + 32, al1);
        gl_lds16(Ab + kk + (size_t)16 * K + 32, al1 + 512);
        gl_lds16(Bb + kk, bl0);
        gl_lds16(Bb + kk + (size_t)16 * K, bl0 + 512);
        gl_lds16(Bb + kk + 32, bl1);
        gl_lds16(Bb + kk + (size_t)16 * K + 32, bl1 + 512);
        __syncthreads();

#pragma unroll
        for (int h = 0; h < 2; h++) {
            short8 af[4], bf8[4];
#pragma unroll
            for (int mt = 0; mt < 4; mt++)
                af[mt] = *(const short8*)(&a_sh[h][(wm * 64 + mt * 16 + l16) * 32 + xo]);
#pragma unroll
            for (int nt = 0; nt < 4; nt++)
                bf8[nt] = *(const short8*)(&b_sh[h][(wn * 64 + nt * 16 + l16) * 32 + xo]);
#pragma unroll
            for (int mt = 0; mt < 4; mt++)
#pragma unroll
                for (int nt = 0; nt < 4; nt++)
                    acc[mt][nt] = __builtin_amdgcn_mfma_f32_16x16x32_bf16(af[mt], bf8[nt], acc[mt][nt], 0, 0, 0);
        }
    }

    u16* Pz = P + (size_t)blockIdx.z * (size_t)M * N;
#pragma unroll
    for (int mt = 0; mt < 4; mt++) {
#pragma unroll
        for (int nt = 0; nt < 4; nt++) {
            int col = n0 + wn * 64 + nt * 16 + l16;
#pragma unroll
            for (int r = 0; r < 4; r++) {
                int row = m0 + wm * 64 + mt * 16 + quad * 4 + r;
                Pz[(size_t)row * N + col] = f2bf(acc[mt][nt][r]);
            }
        }
    }
}

// ---------------- combine 2 bf16 partials + bias + residual -> f32 out ----------------
__global__ __launch_bounds__(256) void combine2_k(
    const u16* __restrict__ P, const float* __restrict__ bias,
    const u16* __restrict__ res, float* __restrict__ out)
{
    const size_t MN = (size_t)TOK * E_;
    size_t i = ((size_t)blockIdx.x * 256 + threadIdx.x) * 8;
    int col = (int)(i & (E_ - 1));
    float v[8];
    f32x4 b0 = *(const f32x4*)(bias + col);
    f32x4 b1 = *(const f32x4*)(bias + col + 4);
    short8 rr = *(const short8*)(res + i);
#pragma unroll
    for (int j = 0; j < 4; j++) { v[j] = b0[j] + bf2f((u16)rr[j]); v[4 + j] = b1[j] + bf2f((u16)rr[4 + j]); }
#pragma unroll
    for (int z = 0; z < 2; z++) {
        short8 p = *(const short8*)(P + z * MN + i);
#pragma unroll
        for (int j = 0; j < 8; j++) v[j] += bf2f((u16)p[j]);
    }
    f32x4 o0, o1;
#pragma unroll
    for (int j = 0; j < 4; j++) { o0[j] = v[j]; o1[j] = v[4 + j]; }
    *(f32x4*)(out + i) = o0;
    *(f32x4*)(out + i + 4) = o1;
}

// ---------------- 128x64 bf16 GEMM BK=64 for N=1024 shapes ----------------
template<int GELU, int RES, int CF32>
__global__ __launch_bounds__(256) void gemm3_k(
    const u16* __restrict__ A, const u16* __restrict__ WT,
    const float* __restrict__ bias, const u16* __restrict__ res,
    void* __restrict__ Cv, int M, int N, int K)
{
    __shared__ __align__(16) short a_sh[2][128 * 32];
    __shared__ __align__(16) short b_sh[2][64 * 32];
    int tid = threadIdx.x;
    int wave = tid >> 6, lane = tid & 63, quad = lane >> 4, l16 = lane & 15;
    int wm = wave >> 1, wn = wave & 1;
    int m0 = blockIdx.y * 128, n0 = blockIdx.x * 64;

    f32x4 acc[4][2];
#pragma unroll
    for (int mt = 0; mt < 4; mt++)
#pragma unroll
        for (int nt = 0; nt < 2; nt++)
            acc[mt][nt] = (f32x4){0.f, 0.f, 0.f, 0.f};

    int srow = lane >> 2;
    int c = ((lane & 3) ^ ((lane >> 3) & 3)) * 8;
    const u16* Ab = A + (size_t)(m0 + wave * 32 + srow) * K + c;
    const u16* Bb = WT + (size_t)(n0 + wave * 16 + srow) * K + c;
    short* al0 = &a_sh[0][wave * 1024];
    short* al1 = &a_sh[1][wave * 1024];
    short* bl0 = &b_sh[0][wave * 512];
    short* bl1 = &b_sh[1][wave * 512];
    int xo = (quad ^ ((l16 >> 1) & 3)) * 8;

    for (int kk = 0; kk < K; kk += 64) {
        __syncthreads();
        gl_lds16(Ab + kk, al0);
        gl_lds16(Ab + kk + (size_t)16 * K, al0 + 512);
        gl_lds16(Ab + kk + 32, al1);
        gl_lds16(Ab + kk + (size_t)16 * K + 32, al1 + 512);
        gl_lds16(Bb + kk, bl0);
        gl_lds16(Bb + kk + 32, bl1);
        __syncthreads();

#pragma unroll
        for (int h = 0; h < 2; h++) {
            short8 af[4], bf8[2];
#pragma unroll
            for (int mt = 0; mt < 4; mt++)
                af[mt] = *(const short8*)(&a_sh[h][(wm * 64 + mt * 16 + l16) * 32 + xo]);
#pragma unroll
            for (int nt = 0; nt < 2; nt++)
                bf8[nt] = *(const short8*)(&b_sh[h][(wn * 32 + nt * 16 + l16) * 32 + xo]);
#pragma unroll
            for (int mt = 0; mt < 4; mt++)
#pragma unroll
                for (int nt = 0; nt < 2; nt++)
                    acc[mt][nt] = __builtin_amdgcn_mfma_f32_16x16x32_bf16(af[mt], bf8[nt], acc[mt][nt], 0, 0, 0);
        }
    }

#pragma unroll
    for (int mt = 0; mt < 4; mt++) {
#pragma unroll
        for (int nt = 0; nt < 2; nt++) {
            int col = n0 + wn * 32 + nt * 16 + l16;
            float bb = bias[col];
#pragma unroll
            for (int r = 0; r < 4; r++) {
                int row = m0 + wm * 64 + mt * 16 + quad * 4 + r;
                float v = acc[mt][nt][r] + bb;
                if (RES) v += bf2f(res[(size_t)row * N + col]);
                if (GELU) v = 0.5f * v * (1.0f + erff(v * 0.70710678118f));
                if (CF32) ((float*)Cv)[(size_t)row * N + col] = v;
                else ((u16*)Cv)[(size_t)row * N + col] = f2bf(v);
            }
        }
    }
}

// ---------------- Flash attention v6: conflict-free P buffer (stride 76) + exp2 ----------------
// LDS-throughput-bound kernel (320KB/CU/kt vs 128B/cyc). Fixes this round:
//  - p_sh stride 72->76 shorts (38 dwords; 38 mod 32 = 6, gcd(6,32)=2 -> all 16 l16
//    lanes hit distinct even banks; residual 2-way aliasing is free). Was ~6
//    conflict-cycles per P-write (3.15M total, ~10% of kernel).
//  - exp2 (v_exp_f32 via __builtin_amdgcn_exp2f): log2(e) folded into the Q
//    pre-scale in the QKV epilogue. Masked lanes: exp2(s - 1e9) = 0, unchanged.
__global__ __launch_bounds__(512) void attn_k(
    const u16* __restrict__ Q, const u16* __restrict__ K,
    const u16* __restrict__ Vt, const float* __restrict__ fb,
    const int* __restrict__ ok, u16* __restrict__ O)
{
    __shared__ __align__(16) short k_sh[2][2][64 * 32];  // [buf][d-half][key][32]
    __shared__ __align__(16) short v_sh[2][2][64 * 32];  // [buf][key-half][d][32]
    __shared__ __align__(16) short p_sh[8][16 * 76];     // per-wave P^T [q][key], stride 76
    int tid = threadIdx.x;
    int wave = tid >> 6, lane = tid & 63, quad = lane >> 4, l16 = lane & 15;
    int lin = blockIdx.x + 16 * (blockIdx.y + 16 * blockIdx.z);
    int xcd = lin & 7, w = lin >> 3;
    int combo = xcd * 4 + (w >> 4);
    int qb = w & 15, h = combo & 15, b = combo >> 4;
    int q0 = qb * 128;
    const u16* Qp = Q + (size_t)b * S_ * E_ + (size_t)h * D_;
    const u16* Kp = K + (size_t)b * S_ * E_ + (size_t)h * D_;
    const u16* Vtp = Vt + (size_t)(b * H_ + h) * D_ * S_;

    int qrow = q0 + wave * 16 + l16;
    short8 qf0 = *(const short8*)(Qp + (size_t)qrow * E_ + quad * 8);
    short8 qf1 = *(const short8*)(Qp + (size_t)qrow * E_ + 32 + quad * 8);

    f32x4 o[4];
#pragma unroll
    for (int dt = 0; dt < 4; dt++) o[dt] = (f32x4){0.f, 0.f, 0.f, 0.f};
    float rs_tot = 0.f;

    int sub = wave & 1, rblk = wave >> 1;
    int srow = lane >> 2;
    int c = ((lane & 3) ^ ((lane >> 3) & 3)) * 8;
    const u16* Kg = Kp + (size_t)(rblk * 16 + srow) * E_ + sub * 32 + c;
    const u16* Vg = Vtp + (size_t)(rblk * 16 + srow) * S_ + sub * 32 + c;
    short* kl0 = &k_sh[0][sub][rblk * 512];
    short* kl1 = &k_sh[1][sub][rblk * 512];
    short* vl0 = &v_sh[0][sub][rblk * 512];
    short* vl1 = &v_sh[1][sub][rblk * 512];

    gl_lds16(Kg, kl0);
    gl_lds16(Vg, vl0);
    __syncthreads();

    const float* fbb = fb + b * S_;
    const int* okb = ok + b * 32;
    int xo = (quad ^ ((l16 >> 1) & 3)) * 8;

    for (int kt = 0; kt < S_ / 64; kt++) {
        int cur = kt & 1;
        if (kt < 31) {
            gl_lds16(Kg + (size_t)(kt + 1) * 64 * E_, cur ? kl0 : kl1);
            gl_lds16(Vg + (kt + 1) * 64, cur ? vl0 : vl1);
        }

        f32x4 s[4];
#pragma unroll
        for (int mt = 0; mt < 4; mt++) {
            int ro = (mt * 16 + l16) * 32 + xo;
            short8 kf0 = *(const short8*)(&k_sh[cur][0][ro]);
            short8 kf1 = *(const short8*)(&k_sh[cur][1][ro]);
            s[mt] = __builtin_amdgcn_mfma_f32_16x16x32_bf16(kf0, qf0, (f32x4){0.f,0.f,0.f,0.f}, 0, 0, 0);
            s[mt] = __builtin_amdgcn_mfma_f32_16x16x32_bf16(kf1, qf1, s[mt], 0, 0, 0);
        }

        if (!okb[kt]) {
#pragma unroll
            for (int mt = 0; mt < 4; mt++)
#pragma unroll
                for (int r = 0; r < 4; r++)
                    s[mt][r] += fbb[kt * 64 + mt * 16 + quad * 4 + r];
        }

#pragma unroll
        for (int mt = 0; mt < 4; mt++) {
            float p0 = EXP2F(s[mt][0]);
            float p1 = EXP2F(s[mt][1]);
            float p2 = EXP2F(s[mt][2]);
            float p3 = EXP2F(s[mt][3]);
            rs_tot += (p0 + p1) + (p2 + p3);
            u32 u0 = __builtin_amdgcn_perm(fbits(p1), fbits(p0), 0x07060302u);
            u32 u1 = __builtin_amdgcn_perm(fbits(p3), fbits(p2), 0x07060302u);
            uint2 pk; pk.x = u0; pk.y = u1;
            *(uint2*)(&p_sh[wave][l16 * 76 + mt * 16 + quad * 4]) = pk;
        }

#pragma unroll
        for (int sk = 0; sk < 2; sk++) {
            short8 pf = *(const short8*)(&p_sh[wave][l16 * 76 + sk * 32 + quad * 8]);
#pragma unroll
            for (int dt = 0; dt < 4; dt++) {
                short8 vf = *(const short8*)(&v_sh[cur][sk][(dt * 16 + l16) * 32 + xo]);
                o[dt] = __builtin_amdgcn_mfma_f32_16x16x32_bf16(vf, pf, o[dt], 0, 0, 0);
            }
        }
        __syncthreads();
    }

    rs_tot += __shfl_xor(rs_tot, 16, 64);
    rs_tot += __shfl_xor(rs_tot, 32, 64);
    float inv = 1.0f / rs_tot;
    u16* Op = O + (size_t)b * S_ * E_ + (size_t)(q0 + wave * 16 + l16) * E_ + h * D_;
#pragma unroll
    for (int dt = 0; dt < 4; dt++) {
        short4_t pk;
#pragma unroll
        for (int r = 0; r < 4; r++) pk[r] = (short)f2bf(o[dt][r] * inv);
        *(short4_t*)(Op + dt * 16 + quad * 4) = pk;
    }
}

extern "C" void kernel_launch(void* const* d_in, const int* in_sizes, int n_in,
                              void* d_out, int out_size, void* d_ws, size_t ws_size,
                              hipStream_t stream)
{
    (void)in_sizes; (void)n_in; (void)out_size; (void)ws_size;
    const float* I      = (const float*)d_in[0];
    const float* x      = (const float*)d_in[1];
    const int*   mask   = (const int*)d_in[2];
    const float* wq     = (const float*)d_in[3];
    const float* bq     = (const float*)d_in[4];
    const float* wk     = (const float*)d_in[5];
    const float* bk     = (const float*)d_in[6];
    const float* wv     = (const float*)d_in[7];
    const float* bv     = (const float*)d_in[8];
    const float* w_proj = (const float*)d_in[9];
    const float* b_proj = (const float*)d_in[10];
    const float* g1     = (const float*)d_in[11];
    const float* be1    = (const float*)d_in[12];
    const float* g2     = (const float*)d_in[13];
    const float* be2    = (const float*)d_in[14];
    const float* w1     = (const float*)d_in[15];
    const float* b1     = (const float*)d_in[16];
    const float* w2     = (const float*)d_in[17];
    const float* b2     = (const float*)d_in[18];
    float* out = (float*)d_out;

    char* ws = (char*)d_ws;
    const size_t SZ = (size_t)TOK * E_;
    u16* xn   = (u16*)(ws);
    u16* qb_  = (u16*)(ws + SZ * 2);
    u16* kb_  = (u16*)(ws + SZ * 4);
    u16* vb_  = (u16*)(ws + SZ * 6);
    u16* Vt   = (u16*)(ws + SZ * 8);
    u16* Ibf  = (u16*)(ws + SZ * 8);
    u16* ctx  = (u16*)(ws + SZ * 6);
    u16* hb   = (u16*)(ws + SZ * 4);
    u16* h2   = (u16*)(ws);
    u16* a1   = (u16*)(ws + SZ * 2);
    u16* WTqkv  = (u16*)(ws + 40u * 1024 * 1024);
    u16* WTproj = (u16*)(ws + 46u * 1024 * 1024);
    u16* WT1    = (u16*)(ws + 48u * 1024 * 1024);
    u16* WT2    = (u16*)(ws + 56u * 1024 * 1024);
    u16* Pp     = (u16*)(ws + 40u * 1024 * 1024);
    float* fbm  = (float*)(ws + 40u * 1024 * 1024);
    int*   okm  = (int*)(ws + 40u * 1024 * 1024 + 16384);

    // Fused prepass: ln1 + convf + all 4 weight transposes + maskprep in ONE launch.
    prep_k<<<dim3(6146), 256, 0, stream>>>(
        I, Ibf, wq, wk, wv, WTqkv, w_proj, WTproj, w1, WT1, w2, WT2,
        mask, fbm, okm, x, g1, be1, xn);

    // QKV: 128x256 BK=32, 2 blocks/CU; grid (12, 32); RX=2
    gemmb32_k<1,0,2><<<dim3(12, TOK / 128), 512, 0, stream>>>(
        Ibf, xn, WTqkv, bq, bk, bv, qb_, TOK, 3072, E_);

    vtrans_k<<<dim3(S_ / 64, H_, B_), 256, 0, stream>>>(vb_, Vt);

    attn_k<<<dim3(S_ / 128, H_, B_), 512, 0, stream>>>(qb_, kb_, Vt, fbm, okm, ctx);

    gemm3_k<0,1,0><<<dim3(16, TOK / 128), 256, 0, stream>>>(
        ctx, WTproj, b_proj, xn, hb, TOK, E_, E_);
    ln_kernel<0><<<TOK / 4, 256, 0, stream>>>(hb, g2, be2, h2);
    // FFN1: 128x256 BK=32, 2 blocks/CU; grid (16, 32); RX=2; fused GELU
    gemmb32_k<0,1,2><<<dim3(16, TOK / 128), 512, 0, stream>>>(
        h2, nullptr, WT1, b1, nullptr, nullptr, a1, TOK, 4 * E_, E_);
    gemmsk_k<<<dim3(8, TOK / 128, 2), 256, 0, stream>>>(
        a1, WT2, Pp, TOK, E_, 4 * E_, 2 * E_);
    combine2_k<<<dim3(TOK * E_ / (256 * 8)), 256, 0, stream>>>(Pp, b2, h2, out);
}